// Round 3
// baseline (289.173 us; speedup 1.0000x reference)
//
#include <hip/hip_runtime.h>
#include <hip/hip_cooperative_groups.h>
#include <math.h>

namespace cg = cooperative_groups;

#define B 8
#define N 1024
#define L 16
#define D 256
#define H 4
#define DH 64
#define NLAYERS 2
#define V 32000

typedef __attribute__((ext_vector_type(8))) short short8;
typedef __attribute__((ext_vector_type(4))) float f32x4;

union U8 { uint4 u; short8 s; };

__device__ inline unsigned short f2bf(float x) {
    unsigned u = __float_as_uint(x);
    u = (u + 0x7fff + ((u >> 16) & 1)) >> 16;  // RNE
    return (unsigned short)u;
}
__device__ inline float bf2f(unsigned short x) {
    return __uint_as_float(((unsigned)x) << 16);
}

// -------- global layouts --------
// WT_sw [lh][d>>5][dh][d&31]  bf16 (B operand of Wh MFMA)   256KB
// WhT   [bh][m>>5][dh][m&31]  bf16 (B operand of attn MFMA) 4MB/layer
// srcv/dstv [bh][n] f32
//
// -------- LDS plan (block = 2 n-tiles of one b, persists across grid.sync) --------
// X region [0,34304): xt[2][16][268] f32 ; aliases nodesLds[512] i32 and dsts[4][1024] f32
// [34304,38400) packs[2][16][16] u64
// [38400,54784) hA[2][8][16][32] bf16   (residual tiles, persist across layers)
#define SM_PACK 34304
#define SM_HA   38400
#define SM_SIZE 54784

// ---- per-wave tile: Wh = h(16x256) @ W(head), write WhT + srcv/dstv ----
__device__ inline void wh_tile(const unsigned short* hA_t,
                               const unsigned short* __restrict__ WT_l,
                               const float* __restrict__ asrc_l,
                               const float* __restrict__ adst_l,
                               unsigned short* __restrict__ WhT_out,
                               float* __restrict__ srcv_out,
                               float* __restrict__ dstv_out,
                               int b, int n0t, int hh, int lane) {
    int rowLane = lane & 15, quad = lane >> 4;
    int bh = b * H + hh;
    const unsigned short* abase = hA_t + rowLane * 32 + quad * 8;
    const unsigned short* bbase = WT_l + (size_t)hh * 16384 + rowLane * 32 + quad * 8;
    f32x4 acc[4] = {};
#pragma unroll
    for (int kc = 0; kc < 8; ++kc) {
        short8 af = *(const short8*)(abase + kc * 512);
#pragma unroll
        for (int c = 0; c < 4; ++c) {
            short8 bf = *(const short8*)(bbase + (size_t)kc * 2048 + c * 512);
            acc[c] = __builtin_amdgcn_mfma_f32_16x16x32_bf16(af, bf, acc[c], 0, 0, 0);
        }
    }
    int m0 = n0t + quad * 4;
    float ps[4] = {0.f, 0.f, 0.f, 0.f}, pd[4] = {0.f, 0.f, 0.f, 0.f};
#pragma unroll
    for (int c = 0; c < 4; ++c) {
        int dh = c * 16 + rowLane;
        ushort4 o;
        o.x = f2bf(acc[c][0]); o.y = f2bf(acc[c][1]);
        o.z = f2bf(acc[c][2]); o.w = f2bf(acc[c][3]);
        *(ushort4*)&WhT_out[(((size_t)bh * 32 + (m0 >> 5)) * 64 + dh) * 32 + (m0 & 31)] = o;
        float as = asrc_l[hh * DH + dh];
        float ad = adst_l[hh * DH + dh];
#pragma unroll
        for (int r = 0; r < 4; ++r) { ps[r] += acc[c][r] * as; pd[r] += acc[c][r] * ad; }
    }
#pragma unroll
    for (int off = 1; off < 16; off <<= 1) {
#pragma unroll
        for (int r = 0; r < 4; ++r) {
            ps[r] += __shfl_xor(ps[r], off, 64);
            pd[r] += __shfl_xor(pd[r], off, 64);
        }
    }
    if (rowLane == 0) {
#pragma unroll
        for (int r = 0; r < 4; ++r) {
            srcv_out[bh * N + m0 + r] = ps[r];
            dstv_out[bh * N + m0 + r] = pd[r];
        }
    }
}

// ---- one attention layer for both tiles + LN (+ next-layer Wh if !FINAL) ----
template <int FINAL>
__device__ inline void attn_phase(char* smem,
                                  const float* __restrict__ srcv_in,
                                  const float* __restrict__ dstv_in,
                                  const unsigned short* __restrict__ WhT_in,
                                  const float* __restrict__ scale_l,
                                  const float* __restrict__ bias_l,
                                  const unsigned short* __restrict__ WT_next,
                                  const float* __restrict__ asrc_n,
                                  const float* __restrict__ adst_n,
                                  unsigned short* __restrict__ WhT_out,
                                  float* __restrict__ srcv_out,
                                  float* __restrict__ dstv_out,
                                  float* __restrict__ out,
                                  int b, int n0base, int tid) {
    float* dsts = (float*)smem;
    const unsigned long long* packs = (const unsigned long long*)(smem + SM_PACK);
    unsigned short* hAall = (unsigned short*)(smem + SM_HA);

    int wg = tid >> 6, lane = tid & 63;
    int tg = wg >> 2, hh = wg & 3;            // tile-group, head
    int rowLane = lane & 15, quad = lane >> 4;
    int bh = b * H + hh;
    int n0t = n0base + tg * 16;

    {   // dsts[hh][0..1023]: the two same-head waves load disjoint halves
        const float* dv = dstv_in + (size_t)bh * N + tg * 512;
#pragma unroll
        for (int k = 0; k < 2; ++k)
            *(float4*)(dsts + hh * 1024 + tg * 512 + k * 256 + lane * 4) =
                *(const float4*)(dv + k * 256 + lane * 4);
    }
    __syncthreads();

    float src = srcv_in[bh * N + n0t + rowLane];
    float mx = src > 0.f ? src : 0.2f * src;           // per-row shift, cancels in softmax
    const unsigned* prow = (const unsigned*)packs + (tg * 16 + rowLane) * 32;
    const unsigned short* wbase = WhT_in + (size_t)bh * 65536 + rowLane * 32 + quad * 8;
    const float* dw = dsts + hh * 1024 + quad * 8;

    f32x4 acc[4] = {};
    float sum0 = 0.f, sum1 = 0.f;
    short8 fb[2][4];
#pragma unroll
    for (int c = 0; c < 4; ++c) fb[0][c] = *(const short8*)(wbase + c * 512);
#pragma unroll 2
    for (int t2 = 0; t2 < 32; ++t2) {
        int cb = t2 & 1;
        int t2n = (t2 + 1) & 31;
#pragma unroll
        for (int c = 0; c < 4; ++c)
            fb[cb ^ 1][c] = *(const short8*)(wbase + (size_t)t2n * 2048 + c * 512);
        unsigned bits = (prow[t2] >> (quad * 8)) & 0xffu;
        float4 d0 = *(const float4*)(dw + t2 * 32);
        float4 d1 = *(const float4*)(dw + t2 * 32 + 4);
        float dd[8] = {d0.x, d0.y, d0.z, d0.w, d1.x, d1.y, d1.z, d1.w};
        unsigned pk[4];
#pragma unroll
        for (int j2 = 0; j2 < 4; ++j2) {
            float ea = src + dd[2 * j2];
            float eb = src + dd[2 * j2 + 1];
            ea = ea > 0.f ? ea : 0.2f * ea;
            eb = eb > 0.f ? eb : 0.2f * eb;
            float pa = ((bits >> (2 * j2)) & 1) ? __expf(ea - mx) : 0.f;
            float pb = ((bits >> (2 * j2 + 1)) & 1) ? __expf(eb - mx) : 0.f;
            sum0 += pa; sum1 += pb;
            pk[j2] = (__float_as_uint(pb) & 0xffff0000u) | (__float_as_uint(pa) >> 16);
        }
        U8 u; u.u = make_uint4(pk[0], pk[1], pk[2], pk[3]);
        short8 af = u.s;
        acc[0] = __builtin_amdgcn_mfma_f32_16x16x32_bf16(af, fb[cb][0], acc[0], 0, 0, 0);
        acc[1] = __builtin_amdgcn_mfma_f32_16x16x32_bf16(af, fb[cb][1], acc[1], 0, 0, 0);
        acc[2] = __builtin_amdgcn_mfma_f32_16x16x32_bf16(af, fb[cb][2], acc[2], 0, 0, 0);
        acc[3] = __builtin_amdgcn_mfma_f32_16x16x32_bf16(af, fb[cb][3], acc[3], 0, 0, 0);
    }
    float sum = sum0 + sum1;
    sum += __shfl_xor(sum, 16, 64);
    sum += __shfl_xor(sum, 32, 64);
    float inv[4];
#pragma unroll
    for (int r = 0; r < 4; ++r) inv[r] = 1.0f / __shfl(sum, quad * 4 + r, 64);

    __syncthreads();   // all waves done reading dsts before xt overwrite
    float* xt = (float*)smem + tg * 4288;
#pragma unroll
    for (int c = 0; c < 4; ++c)
#pragma unroll
        for (int r = 0; r < 4; ++r)
            xt[(quad * 4 + r) * 268 + hh * 64 + c * 16 + rowLane] = acc[c][r] * inv[r];
    __syncthreads();

    // ---- LN: 512 threads = 2 tiles x (row = 0..15, g = 0..15), 16 cols each ----
    int t8 = tid >> 8, rowg = tid & 255;
    int row = rowg >> 4, g = rowg & 15;
    const float* xtt = (float*)smem + t8 * 4288;
    unsigned short* ha = hAall + t8 * 4096 + (g >> 1) * 512 + row * 32 + (g & 1) * 16;
    U8 r0, r1;
    r0.u = *(const uint4*)ha;
    r1.u = *(const uint4*)(ha + 8);
    float4 xr[4];
#pragma unroll
    for (int k = 0; k < 4; ++k) xr[k] = *(const float4*)(xtt + row * 268 + g * 16 + k * 4);
    float xv[16];
    float s = 0.f, s2 = 0.f;
#pragma unroll
    for (int j = 0; j < 16; ++j) {
        unsigned short hv = (j < 8) ? ((const unsigned short*)&r0)[j] : ((const unsigned short*)&r1)[j - 8];
        float x = bf2f(hv) + ((const float*)xr)[j];
        xv[j] = x; s += x; s2 += x * x;
    }
#pragma unroll
    for (int off = 1; off < 16; off <<= 1) {
        s += __shfl_xor(s, off, 64);
        s2 += __shfl_xor(s2, off, 64);
    }
    float mu = s * (1.0f / D);
    float var = s2 * (1.0f / D) - mu * mu;
    float rstd = rsqrtf(var + 1e-5f);
    int d0 = g * 16;
    if (FINAL) {
        float* orow = out + ((size_t)(b * N) + n0base + t8 * 16 + row) * D + d0;
#pragma unroll
        for (int k = 0; k < 4; ++k) {
            float4 sc = *(const float4*)(scale_l + d0 + k * 4);
            float4 bi = *(const float4*)(bias_l + d0 + k * 4);
            float4 y;
            y.x = (xv[k * 4 + 0] - mu) * rstd * sc.x + bi.x;
            y.y = (xv[k * 4 + 1] - mu) * rstd * sc.y + bi.y;
            y.z = (xv[k * 4 + 2] - mu) * rstd * sc.z + bi.z;
            y.w = (xv[k * 4 + 3] - mu) * rstd * sc.w + bi.w;
            *(float4*)(orow + k * 4) = y;
        }
    } else {
        U8 o0, o1;
#pragma unroll
        for (int j = 0; j < 16; ++j) {
            float scv = scale_l[d0 + j];
            float biv = bias_l[d0 + j];
            unsigned short yb = f2bf((xv[j] - mu) * rstd * scv + biv);
            if (j < 8) ((unsigned short*)&o0)[j] = yb;
            else ((unsigned short*)&o1)[j - 8] = yb;
        }
        *(uint4*)ha = o0.u;          // new residual, LDS only (thread-bijective)
        *(uint4*)(ha + 8) = o1.u;
        __syncthreads();
        wh_tile(hAall + tg * 4096, WT_next, asrc_n, adst_n, WhT_out, srcv_out, dstv_out,
                b, n0t, hh, lane);
    }
}

// ---- whole model, one cooperative kernel: 256 blocks x 512 thr = 1 block/CU ----
__global__ __launch_bounds__(512, 2) void k_mega(
    const int* __restrict__ adj, const float* __restrict__ W,
    const int* __restrict__ len, const float* __restrict__ emb,
    const int* __restrict__ nodes,
    const float* __restrict__ a_src, const float* __restrict__ a_dst,
    const float* __restrict__ ln_scale, const float* __restrict__ ln_bias,
    float* __restrict__ out,
    unsigned short* __restrict__ WT_sw,
    unsigned short* __restrict__ WhT0, unsigned short* __restrict__ WhT1,
    float* __restrict__ srcv0, float* __restrict__ dstv0,
    float* __restrict__ srcv1, float* __restrict__ dstv1) {
    __shared__ __align__(16) char smem[SM_SIZE];
    int* nodesLds = (int*)smem;
    unsigned long long* packs = (unsigned long long*)(smem + SM_PACK);
    unsigned short* hAall = (unsigned short*)(smem + SM_HA);

    cg::grid_group grid = cg::this_grid();
    int tid = threadIdx.x;
    int bt = blockIdx.x;
    int b = bt >> 5, ntPair = bt & 31, n0base = ntPair * 32;
    int wg = tid >> 6, lane = tid & 63;
    int tg = wg >> 2, hh = wg & 3;

    // ---- phase 0: gather/mean -> hA, adjacency pack -> packs, WT transpose, len ----
    nodesLds[tid] = nodes[((size_t)(b * N + n0base)) * L + tid];
    __syncthreads();
    {
        int d4 = lane * 4;
#pragma unroll
        for (int r = 0; r < 4; ++r) {          // wave wg handles rows wg*4 .. wg*4+3 (of 32)
            int r16 = wg * 4 + r;
            const int* np = nodesLds + r16 * L;
            float4 s = make_float4(0.f, 0.f, 0.f, 0.f);
#pragma unroll
            for (int l = 0; l < L; ++l) {
                float4 v = *(const float4*)&emb[(size_t)np[l] * D + d4];
                s.x += v.x; s.y += v.y; s.z += v.z; s.w += v.w;
            }
            ushort4 o;
            o.x = f2bf(s.x * (1.0f / L)); o.y = f2bf(s.y * (1.0f / L));
            o.z = f2bf(s.z * (1.0f / L)); o.w = f2bf(s.w * (1.0f / L));
            *(ushort4*)&hAall[(r16 >> 4) * 4096 + (d4 >> 5) * 512 + (r16 & 15) * 32 + (d4 & 31)] = o;
        }
    }
    {
        int g16 = lane & 15;
#pragma unroll
        for (int r = 0; r < 4; ++r) {
            int r16 = wg * 4 + r;
            int n = n0base + r16;
            const int* arow = adj + ((size_t)(b * N + n)) * N;
#pragma unroll
            for (int it = 0; it < 4; ++it) {
                int m0 = it * 256 + lane * 4;
                int4 a = *(const int4*)(arow + m0);
                unsigned nib = (unsigned)((a.x != 0) || (m0 == n))
                             | ((unsigned)((a.y != 0) || (m0 + 1 == n)) << 1)
                             | ((unsigned)((a.z != 0) || (m0 + 2 == n)) << 2)
                             | ((unsigned)((a.w != 0) || (m0 + 3 == n)) << 3);
                unsigned long long v = (unsigned long long)nib << (g16 * 4);
                v |= __shfl_xor(v, 1, 64);
                v |= __shfl_xor(v, 2, 64);
                v |= __shfl_xor(v, 4, 64);
                v |= __shfl_xor(v, 8, 64);
                if (g16 == 0) packs[r16 * 16 + it * 4 + (lane >> 4)] = v;
            }
        }
    }
    if (bt < NLAYERS * H * 4) {               // WT transpose: 32 blocks, 512 thr each
        int lh = bt >> 2, q = bt & 3;
        const float* Wl = W + (size_t)lh * D * DH;
        int dh = tid & 63;
        int d0 = q * 64 + (tid >> 6) * 8;
#pragma unroll
        for (int i = 0; i < 8; ++i) {
            int d = d0 + i;
            WT_sw[(((size_t)lh * 8 + (d >> 5)) * 64 + dh) * 32 + (d & 31)] = f2bf(Wl[(size_t)d * DH + dh]);
        }
    }
    if (bt == 32 && tid < B) out[(size_t)B * N * D + tid] = (float)len[tid];

    grid.sync();
    // ---- phase 0b: layer-0 Wh (needs WT_sw grid-wide) ----
    wh_tile(hAall + tg * 4096, WT_sw, a_src, a_dst, WhT0, srcv0, dstv0,
            b, n0base + tg * 16, hh, lane);
    grid.sync();
    // ---- phase 1: layer-0 attention + LN + layer-1 Wh ----
    attn_phase<0>(smem, srcv0, dstv0, WhT0,
                  ln_scale, ln_bias,
                  WT_sw + (size_t)H * 16384, a_src + (size_t)H * DH, a_dst + (size_t)H * DH,
                  WhT1, srcv1, dstv1, nullptr, b, n0base, tid);
    grid.sync();
    // ---- phase 2: layer-1 attention + final LN -> out ----
    attn_phase<1>(smem, srcv1, dstv1, WhT1,
                  ln_scale + D, ln_bias + D,
                  nullptr, nullptr, nullptr,
                  nullptr, nullptr, nullptr, out, b, n0base, tid);
}

extern "C" void kernel_launch(void* const* d_in, const int* in_sizes, int n_in,
                              void* d_out, int out_size, void* d_ws, size_t ws_size,
                              hipStream_t stream) {
    const int* cfg_adj = (const int*)d_in[0];
    const int* cfg_nodes = (const int*)d_in[1];
    const int* cfg_len = (const int*)d_in[2];
    const float* emb = (const float*)d_in[3];
    const float* W = (const float*)d_in[4];
    const float* a_src = (const float*)d_in[5];
    const float* a_dst = (const float*)d_in[6];
    const float* ln_scale = (const float*)d_in[7];
    const float* ln_bias = (const float*)d_in[8];
    float* out = (float*)d_out;
    float* ws = (float*)d_ws;

    float* srcv0 = ws;
    float* dstv0 = srcv0 + (size_t)B * H * N;
    float* srcv1 = dstv0 + (size_t)B * H * N;
    float* dstv1 = srcv1 + (size_t)B * H * N;
    unsigned short* WhT0 = (unsigned short*)(dstv1 + (size_t)B * H * N);
    unsigned short* WhT1 = WhT0 + (size_t)B * H * DH * N;
    unsigned short* WT_sw = WhT1 + (size_t)B * H * DH * N;

    void* args[] = {(void*)&cfg_adj, (void*)&W, (void*)&cfg_len, (void*)&emb,
                    (void*)&cfg_nodes, (void*)&a_src, (void*)&a_dst,
                    (void*)&ln_scale, (void*)&ln_bias, (void*)&out,
                    (void*)&WT_sw, (void*)&WhT0, (void*)&WhT1,
                    (void*)&srcv0, (void*)&dstv0, (void*)&srcv1, (void*)&dstv1};
    hipLaunchCooperativeKernel((void*)k_mega, dim3(B * 32), dim3(512), args, 0, stream);
}

// Round 4
// 209.571 us; speedup vs baseline: 1.3798x; 1.3798x over previous
//
#include <hip/hip_runtime.h>
#include <math.h>

#define B 8
#define N 1024
#define L 16
#define D 256
#define H 4
#define DH 64
#define NLAYERS 2
#define V 32000

typedef __attribute__((ext_vector_type(8))) short short8;
typedef __attribute__((ext_vector_type(4))) float f32x4;

union U8 { uint4 u; short8 s; };

__device__ inline unsigned short f2bf(float x) {
    unsigned u = __float_as_uint(x);
    u = (u + 0x7fff + ((u >> 16) & 1)) >> 16;  // RNE
    return (unsigned short)u;
}
__device__ inline float bf2f(unsigned short x) {
    return __uint_as_float(((unsigned)x) << 16);
}

// -------- layouts --------
// h_sw  [b][n>>4][d>>5][n&15][d&31]  bf16  residual stream
// WT_sw [h][d>>5][dh][d&31]          bf16  LAYER-1 ONLY (B operand of wh1 MFMA)
// WhT   [bh][m>>5][dh][m&31]         bf16  (B operand of attn MFMA)
// pack  [b][n][m/64]                 u64 adjacency (+self-loop)

// ---- K1: feat gather + adjacency pack + layer-0 Wh (reg-loaded W) + layer-1 WT + len ----
__global__ __launch_bounds__(256) void k_fpw(
    const float* __restrict__ emb, const int* __restrict__ nodes,
    const int* __restrict__ adj, const int* __restrict__ len,
    const float* __restrict__ W,
    const float* __restrict__ a_src, const float* __restrict__ a_dst,
    unsigned short* __restrict__ h_sw, unsigned long long* __restrict__ pack,
    unsigned short* __restrict__ WT_sw,
    unsigned short* __restrict__ WhT0, float* __restrict__ srcv0, float* __restrict__ dstv0,
    float* __restrict__ out_len) {
    int bt = blockIdx.x, tid = threadIdx.x;
    if (bt >= 512) {                       // 16 blocks: layer-1 WT transpose (consumed by K2)
        int idx = bt - 512;
        int hh = idx >> 2, q = idx & 3;
        const float* Wl = W + (size_t)(H + hh) * D * DH;
        int dh = tid & 63;
        int d0 = q * 64 + (tid >> 6) * 16;
#pragma unroll
        for (int i = 0; i < 16; ++i) {
            int d = d0 + i;
            WT_sw[(((size_t)hh * 8 + (d >> 5)) * 64 + dh) * 32 + (d & 31)] = f2bf(Wl[(size_t)d * DH + dh]);
        }
        return;
    }
    __shared__ __align__(16) int nodesLds[256];
    __shared__ __align__(16) unsigned short hA[4096];
    int b = bt >> 6, nt = bt & 63, n0 = nt * 16;
    if (bt == 0 && tid < B) out_len[tid] = (float)len[tid];
    nodesLds[tid] = nodes[((size_t)(b * N + n0)) * L + tid];
    __syncthreads();

    // ---- gather/mean: thread = (row = tid>>4, colgroup cg = tid&15 -> d = cg*16..+15) ----
    {
        int row = tid >> 4, cg = tid & 15;
        const int* np = nodesLds + row * L;
        float4 a0 = make_float4(0.f, 0.f, 0.f, 0.f), a1 = a0, a2 = a0, a3 = a0;
#pragma unroll
        for (int l = 0; l < L; ++l) {
            const float* e = emb + (size_t)np[l] * D + cg * 16;
            float4 v0 = *(const float4*)(e);
            float4 v1 = *(const float4*)(e + 4);
            float4 v2 = *(const float4*)(e + 8);
            float4 v3 = *(const float4*)(e + 12);
            a0.x += v0.x; a0.y += v0.y; a0.z += v0.z; a0.w += v0.w;
            a1.x += v1.x; a1.y += v1.y; a1.z += v1.z; a1.w += v1.w;
            a2.x += v2.x; a2.y += v2.y; a2.z += v2.z; a2.w += v2.w;
            a3.x += v3.x; a3.y += v3.y; a3.z += v3.z; a3.w += v3.w;
        }
        const float sc = 1.0f / L;
        U8 o0, o1;
        float f0[8] = {a0.x, a0.y, a0.z, a0.w, a1.x, a1.y, a1.z, a1.w};
        float f1[8] = {a2.x, a2.y, a2.z, a2.w, a3.x, a3.y, a3.z, a3.w};
#pragma unroll
        for (int j = 0; j < 8; ++j) {
            ((unsigned short*)&o0)[j] = f2bf(f0[j] * sc);
            ((unsigned short*)&o1)[j] = f2bf(f1[j] * sc);
        }
        size_t lbase = ((size_t)(cg >> 1)) * 512 + row * 32 + (cg & 1) * 16;
        *(uint4*)&hA[lbase] = o0.u;
        *(uint4*)&hA[lbase + 8] = o1.u;
        size_t gbase = ((size_t)(b * 64 + nt)) * 4096 + lbase;
        *(uint4*)&h_sw[gbase] = o0.u;
        *(uint4*)&h_sw[gbase + 8] = o1.u;
    }

    // ---- adjacency pack: wave w packs rows w*4..w*4+3 ----
    {
        int w = tid >> 6, lane = tid & 63, g16 = lane & 15;
#pragma unroll
        for (int r = 0; r < 4; ++r) {
            int r16 = w * 4 + r;
            int n = n0 + r16;
            const int* arow = adj + ((size_t)(b * N + n)) * N;
            unsigned long long* prow = pack + ((size_t)(b * N + n)) * 16;
#pragma unroll
            for (int it = 0; it < 4; ++it) {
                int m0 = it * 256 + lane * 4;
                int4 a = *(const int4*)(arow + m0);
                unsigned nib = (unsigned)((a.x != 0) || (m0 == n))
                             | ((unsigned)((a.y != 0) || (m0 + 1 == n)) << 1)
                             | ((unsigned)((a.z != 0) || (m0 + 2 == n)) << 2)
                             | ((unsigned)((a.w != 0) || (m0 + 3 == n)) << 3);
                unsigned long long v = (unsigned long long)nib << (g16 * 4);
                v |= __shfl_xor(v, 1, 64);
                v |= __shfl_xor(v, 2, 64);
                v |= __shfl_xor(v, 4, 64);
                v |= __shfl_xor(v, 8, 64);
                if (g16 == 0) prow[it * 4 + (lane >> 4)] = v;
            }
        }
    }
    __syncthreads();

    // ---- layer-0 Wh: wave = head, B-frags loaded from fp32 W directly ----
    {
        int w = tid >> 6, lane = tid & 63;
        int rowLane = lane & 15, quad = lane >> 4;
        int bh = b * H + w;
        const float* W0 = W + (size_t)w * D * DH;   // layer 0, head w
        const float* wb = W0 + (size_t)(quad * 8) * DH + rowLane;
        short8 bfr[8][4];
#pragma unroll
        for (int kc = 0; kc < 8; ++kc)
#pragma unroll
            for (int c = 0; c < 4; ++c) {
                short8 f;
#pragma unroll
                for (int j = 0; j < 8; ++j)
                    f[j] = (short)f2bf(wb[(size_t)(kc * 32 + j) * DH + c * 16]);
                bfr[kc][c] = f;
            }
        const unsigned short* abase = hA + rowLane * 32 + quad * 8;
        f32x4 acc[4] = {};
#pragma unroll
        for (int kc = 0; kc < 8; ++kc) {
            short8 af = *(const short8*)(abase + kc * 512);
#pragma unroll
            for (int c = 0; c < 4; ++c)
                acc[c] = __builtin_amdgcn_mfma_f32_16x16x32_bf16(af, bfr[kc][c], acc[c], 0, 0, 0);
        }
        int m0 = n0 + quad * 4;
        float ps[4] = {0.f, 0.f, 0.f, 0.f}, pd[4] = {0.f, 0.f, 0.f, 0.f};
#pragma unroll
        for (int c = 0; c < 4; ++c) {
            int dh = c * 16 + rowLane;
            ushort4 o;
            o.x = f2bf(acc[c][0]); o.y = f2bf(acc[c][1]);
            o.z = f2bf(acc[c][2]); o.w = f2bf(acc[c][3]);
            *(ushort4*)&WhT0[(((size_t)bh * 32 + (m0 >> 5)) * 64 + dh) * 32 + (m0 & 31)] = o;
            float as = a_src[w * DH + dh];
            float ad = a_dst[w * DH + dh];
#pragma unroll
            for (int r = 0; r < 4; ++r) { ps[r] += acc[c][r] * as; pd[r] += acc[c][r] * ad; }
        }
#pragma unroll
        for (int off = 1; off < 16; off <<= 1) {
#pragma unroll
            for (int r = 0; r < 4; ++r) {
                ps[r] += __shfl_xor(ps[r], off, 64);
                pd[r] += __shfl_xor(pd[r], off, 64);
            }
        }
        if (rowLane == 0) {
#pragma unroll
            for (int r = 0; r < 4; ++r) {
                srcv0[bh * N + m0 + r] = ps[r];
                dstv0[bh * N + m0 + r] = pd[r];
            }
        }
    }
}

// ---- per-wave tile: Wh = h(16x256) @ W(head) from LDS WT, write WhT + srcv/dstv ----
__device__ inline void wh_tile(const unsigned short* hA_t,
                               const unsigned short* __restrict__ WT_l,
                               const float* __restrict__ asrc_l,
                               const float* __restrict__ adst_l,
                               unsigned short* __restrict__ WhT_out,
                               float* __restrict__ srcv_out,
                               float* __restrict__ dstv_out,
                               int b, int n0t, int hh, int lane) {
    int rowLane = lane & 15, quad = lane >> 4;
    int bh = b * H + hh;
    const unsigned short* abase = hA_t + rowLane * 32 + quad * 8;
    const unsigned short* bbase = WT_l + (size_t)hh * 16384 + rowLane * 32 + quad * 8;
    f32x4 acc[4] = {};
#pragma unroll
    for (int kc = 0; kc < 8; ++kc) {
        short8 af = *(const short8*)(abase + kc * 512);
#pragma unroll
        for (int c = 0; c < 4; ++c) {
            short8 bf = *(const short8*)(bbase + (size_t)kc * 2048 + c * 512);
            acc[c] = __builtin_amdgcn_mfma_f32_16x16x32_bf16(af, bf, acc[c], 0, 0, 0);
        }
    }
    int m0 = n0t + quad * 4;
    float ps[4] = {0.f, 0.f, 0.f, 0.f}, pd[4] = {0.f, 0.f, 0.f, 0.f};
#pragma unroll
    for (int c = 0; c < 4; ++c) {
        int dh = c * 16 + rowLane;
        ushort4 o;
        o.x = f2bf(acc[c][0]); o.y = f2bf(acc[c][1]);
        o.z = f2bf(acc[c][2]); o.w = f2bf(acc[c][3]);
        *(ushort4*)&WhT_out[(((size_t)bh * 32 + (m0 >> 5)) * 64 + dh) * 32 + (m0 & 31)] = o;
        float as = asrc_l[hh * DH + dh];
        float ad = adst_l[hh * DH + dh];
#pragma unroll
        for (int r = 0; r < 4; ++r) { ps[r] += acc[c][r] * as; pd[r] += acc[c][r] * ad; }
    }
#pragma unroll
    for (int off = 1; off < 16; off <<= 1) {
#pragma unroll
        for (int r = 0; r < 4; ++r) {
            ps[r] += __shfl_xor(ps[r], off, 64);
            pd[r] += __shfl_xor(pd[r], off, 64);
        }
    }
    if (rowLane == 0) {
#pragma unroll
        for (int r = 0; r < 4; ++r) {
            srcv_out[bh * N + m0 + r] = ps[r];
            dstv_out[bh * N + m0 + r] = pd[r];
        }
    }
}

// ---- K2/K3: attention (wave=head, full m sweep) + LN + next-layer Wh fused ----
template <int FINAL>
__global__ __launch_bounds__(256) void k_attn_f(const unsigned long long* __restrict__ pack,
                                                const float* __restrict__ srcv_in,
                                                const float* __restrict__ dstv_in,
                                                const unsigned short* __restrict__ WhT_in,
                                                unsigned short* __restrict__ h_sw,
                                                const float* __restrict__ scale_l,
                                                const float* __restrict__ bias_l,
                                                const unsigned short* __restrict__ WT_next,
                                                const float* __restrict__ asrc_n,
                                                const float* __restrict__ adst_n,
                                                unsigned short* __restrict__ WhT_out,
                                                float* __restrict__ srcv_out,
                                                float* __restrict__ dstv_out,
                                                float* __restrict__ out) {
    // smem plan: [0,16384) dsts[4][1024] f32 ; [16384,18432) pack[16][16] u64
    //            after sync: [0,17152) xt[16][268] f32 ; [17408,25600) hA[8][16][32] bf16
    __shared__ __align__(16) char smem[25600];
    float* dsts = (float*)smem;
    unsigned long long* packs = (unsigned long long*)(smem + 16384);
    float* xt = (float*)smem;
    unsigned short* hA = (unsigned short*)(smem + 17408);

    int tid = threadIdx.x;
    int bt = blockIdx.x;
    int b = bt >> 6, nt = bt & 63, n0 = nt * 16;
    int w = tid >> 6, lane = tid & 63;      // w = head
    int rowLane = lane & 15, quad = lane >> 4;
    int bh = b * H + w;

    {
        const float* dv = dstv_in + (size_t)bh * N;
#pragma unroll
        for (int k = 0; k < 4; ++k)
            *(float4*)(dsts + w * 1024 + k * 256 + lane * 4) = *(const float4*)(dv + k * 256 + lane * 4);
        packs[tid] = pack[((size_t)(b * N + n0 + (tid >> 4))) * 16 + (tid & 15)];
    }
    __syncthreads();

    float src = srcv_in[bh * N + n0 + rowLane];
    float mx = src > 0.f ? src : 0.2f * src;           // per-row shift, cancels in softmax
    const unsigned* prow = (const unsigned*)packs + rowLane * 32;
    const unsigned short* wbase = WhT_in + (size_t)bh * 65536 + rowLane * 32 + quad * 8;
    const float* dw = dsts + w * 1024 + quad * 8;

    f32x4 acc[4] = {};
    float sum0 = 0.f, sum1 = 0.f;
    short8 fb[2][4];
#pragma unroll
    for (int c = 0; c < 4; ++c) fb[0][c] = *(const short8*)(wbase + c * 512);
#pragma unroll 2
    for (int t2 = 0; t2 < 32; ++t2) {
        int cb = t2 & 1;
        int t2n = (t2 + 1) & 31;
#pragma unroll
        for (int c = 0; c < 4; ++c)
            fb[cb ^ 1][c] = *(const short8*)(wbase + (size_t)t2n * 2048 + c * 512);
        unsigned bits = (prow[t2] >> (quad * 8)) & 0xffu;
        float4 d0 = *(const float4*)(dw + t2 * 32);
        float4 d1 = *(const float4*)(dw + t2 * 32 + 4);
        float dd[8] = {d0.x, d0.y, d0.z, d0.w, d1.x, d1.y, d1.z, d1.w};
        unsigned pk[4];
#pragma unroll
        for (int j2 = 0; j2 < 4; ++j2) {
            float ea = src + dd[2 * j2];
            float eb = src + dd[2 * j2 + 1];
            ea = ea > 0.f ? ea : 0.2f * ea;
            eb = eb > 0.f ? eb : 0.2f * eb;
            float pa = ((bits >> (2 * j2)) & 1) ? __expf(ea - mx) : 0.f;
            float pb = ((bits >> (2 * j2 + 1)) & 1) ? __expf(eb - mx) : 0.f;
            sum0 += pa; sum1 += pb;
            pk[j2] = (__float_as_uint(pb) & 0xffff0000u) | (__float_as_uint(pa) >> 16);
        }
        U8 u; u.u = make_uint4(pk[0], pk[1], pk[2], pk[3]);
        short8 af = u.s;
        acc[0] = __builtin_amdgcn_mfma_f32_16x16x32_bf16(af, fb[cb][0], acc[0], 0, 0, 0);
        acc[1] = __builtin_amdgcn_mfma_f32_16x16x32_bf16(af, fb[cb][1], acc[1], 0, 0, 0);
        acc[2] = __builtin_amdgcn_mfma_f32_16x16x32_bf16(af, fb[cb][2], acc[2], 0, 0, 0);
        acc[3] = __builtin_amdgcn_mfma_f32_16x16x32_bf16(af, fb[cb][3], acc[3], 0, 0, 0);
    }
    float sum = sum0 + sum1;
    sum += __shfl_xor(sum, 16, 64);
    sum += __shfl_xor(sum, 32, 64);
    float inv[4];
#pragma unroll
    for (int r = 0; r < 4; ++r) inv[r] = 1.0f / __shfl(sum, quad * 4 + r, 64);

    __syncthreads();   // all waves done reading dsts before xt overwrite
#pragma unroll
    for (int c = 0; c < 4; ++c)
#pragma unroll
        for (int r = 0; r < 4; ++r)
            xt[(quad * 4 + r) * 268 + w * 64 + c * 16 + rowLane] = acc[c][r] * inv[r];
    __syncthreads();

    // ---- LN: thread = (row = tid>>4, g = tid&15), 16 cols each; residual from h_sw ----
    int row = tid >> 4, g = tid & 15;
    size_t hsb = ((size_t)(b * 64 + nt) * 8 + (g >> 1)) * 512 + row * 32 + (g & 1) * 16;
    U8 r0, r1;
    r0.u = *(const uint4*)(h_sw + hsb);
    r1.u = *(const uint4*)(h_sw + hsb + 8);
    float4 xr[4];
#pragma unroll
    for (int k = 0; k < 4; ++k) xr[k] = *(const float4*)(xt + row * 268 + g * 16 + k * 4);
    float xv[16];
    float s = 0.f, s2 = 0.f;
#pragma unroll
    for (int j = 0; j < 16; ++j) {
        unsigned short hv = (j < 8) ? ((const unsigned short*)&r0)[j] : ((const unsigned short*)&r1)[j - 8];
        float x = bf2f(hv) + ((const float*)xr)[j];
        xv[j] = x; s += x; s2 += x * x;
    }
#pragma unroll
    for (int off = 1; off < 16; off <<= 1) {
        s += __shfl_xor(s, off, 64);
        s2 += __shfl_xor(s2, off, 64);
    }
    float mu = s * (1.0f / D);
    float var = s2 * (1.0f / D) - mu * mu;
    float rstd = rsqrtf(var + 1e-5f);
    int d0 = g * 16;
    if (FINAL) {
        float* orow = out + ((size_t)(b * N) + n0 + row) * D + d0;
#pragma unroll
        for (int k = 0; k < 4; ++k) {
            float4 sc = *(const float4*)(scale_l + d0 + k * 4);
            float4 bi = *(const float4*)(bias_l + d0 + k * 4);
            float4 y;
            y.x = (xv[k * 4 + 0] - mu) * rstd * sc.x + bi.x;
            y.y = (xv[k * 4 + 1] - mu) * rstd * sc.y + bi.y;
            y.z = (xv[k * 4 + 2] - mu) * rstd * sc.z + bi.z;
            y.w = (xv[k * 4 + 3] - mu) * rstd * sc.w + bi.w;
            *(float4*)(orow + k * 4) = y;
        }
    } else {
        U8 o0, o1;
#pragma unroll
        for (int j = 0; j < 16; ++j) {
            float scv = scale_l[d0 + j];
            float biv = bias_l[d0 + j];
            unsigned short yb = f2bf((xv[j] - mu) * rstd * scv + biv);
            if (j < 8) ((unsigned short*)&o0)[j] = yb;
            else ((unsigned short*)&o1)[j - 8] = yb;
        }
        *(uint4*)(h_sw + hsb) = o0.u;
        *(uint4*)(h_sw + hsb + 8) = o1.u;
        unsigned short* ha = hA + (g >> 1) * 512 + row * 32 + (g & 1) * 16;
        *(uint4*)ha = o0.u;
        *(uint4*)(ha + 8) = o1.u;
        __syncthreads();
        wh_tile(hA, WT_next, asrc_n, adst_n, WhT_out, srcv_out, dstv_out, b, n0, w, lane);
    }
}

extern "C" void kernel_launch(void* const* d_in, const int* in_sizes, int n_in,
                              void* d_out, int out_size, void* d_ws, size_t ws_size,
                              hipStream_t stream) {
    const int* cfg_adj = (const int*)d_in[0];
    const int* cfg_nodes = (const int*)d_in[1];
    const int* cfg_len = (const int*)d_in[2];
    const float* emb = (const float*)d_in[3];
    const float* W = (const float*)d_in[4];
    const float* a_src = (const float*)d_in[5];
    const float* a_dst = (const float*)d_in[6];
    const float* ln_scale = (const float*)d_in[7];
    const float* ln_bias = (const float*)d_in[8];
    float* out = (float*)d_out;
    float* ws = (float*)d_ws;

    float* srcv0 = ws;
    float* dstv0 = srcv0 + (size_t)B * H * N;
    float* srcv1 = dstv0 + (size_t)B * H * N;
    float* dstv1 = srcv1 + (size_t)B * H * N;
    unsigned short* h_sw = (unsigned short*)(dstv1 + (size_t)B * H * N);
    unsigned short* WhT0 = h_sw + (size_t)B * N * D;
    unsigned short* WhT1 = WhT0 + (size_t)B * H * DH * N;
    unsigned short* WT_sw = WhT1 + (size_t)B * H * DH * N;   // layer-1 only, H*D*DH
    unsigned long long* pack = (unsigned long long*)(WT_sw + (size_t)H * D * DH);

    k_fpw<<<512 + 16, 256, 0, stream>>>(emb, cfg_nodes, cfg_adj, cfg_len, W,
                                        a_src, a_dst, h_sw, pack, WT_sw,
                                        WhT0, srcv0, dstv0, out + (size_t)B * N * D);
    k_attn_f<0><<<B * 64, 256, 0, stream>>>(pack, srcv0, dstv0, WhT0, h_sw,
                                            ln_scale, ln_bias,
                                            WT_sw,
                                            a_src + (size_t)H * DH, a_dst + (size_t)H * DH,
                                            WhT1, srcv1, dstv1, nullptr);
    k_attn_f<1><<<B * 64, 256, 0, stream>>>(pack, srcv1, dstv1, WhT1, h_sw,
                                            ln_scale + D, ln_bias + D,
                                            nullptr, nullptr, nullptr,
                                            nullptr, nullptr, nullptr, out);
}

// Round 5
// 176.675 us; speedup vs baseline: 1.6367x; 1.1862x over previous
//
#include <hip/hip_runtime.h>
#include <math.h>

#define B 8
#define N 1024
#define L 16
#define D 256
#define H 4
#define DH 64
#define NLAYERS 2
#define V 32000

typedef __attribute__((ext_vector_type(8))) short short8;
typedef __attribute__((ext_vector_type(4))) float f32x4;

union U8 { uint4 u; short8 s; };

__device__ inline unsigned short f2bf(float x) {
    unsigned u = __float_as_uint(x);
    u = (u + 0x7fff + ((u >> 16) & 1)) >> 16;  // RNE
    return (unsigned short)u;
}
__device__ inline float bf2f(unsigned short x) {
    return __uint_as_float(((unsigned)x) << 16);
}

// -------- layouts --------
// h_sw  [b][n>>4][d>>5][n&15][d&31]  bf16  residual stream
// WT_sw [lh][d>>5][dh][d&31]         bf16  both layers (B operand of Wh MFMA)
// WhT   [bh][m>>5][dh][m&31]         bf16  (B operand of attn MFMA)
// pack  [b][n][m/64]                 u64 adjacency (+self-loop)

// ---- K1: WT transpose (both layers) + len. 9 blocks x 1024 thr (tiny). ----
__global__ __launch_bounds__(1024) void k_pre(const float* __restrict__ W,
                                              const int* __restrict__ len,
                                              unsigned short* __restrict__ WT_sw,
                                              float* __restrict__ out_len) {
    int bt = blockIdx.x, tid = threadIdx.x;
    if (bt < NLAYERS * H) {
        int lh = bt;
        const float* Wl = W + (size_t)lh * D * DH;
        int dh = tid & 63;
        int d0 = (tid >> 6) * 16;
#pragma unroll
        for (int i = 0; i < 16; ++i) {
            int d = d0 + i;
            WT_sw[(((size_t)lh * 8 + (d >> 5)) * 64 + dh) * 32 + (d & 31)] = f2bf(Wl[(size_t)d * DH + dh]);
        }
    } else {
        if (tid < B) out_len[tid] = (float)len[tid];
    }
}

// ---- per-wave tile: Wh = h(16x256) @ W(head) from LDS/global WT, write WhT + srcv/dstv ----
__device__ inline void wh_tile(const unsigned short* hA_t,
                               const unsigned short* __restrict__ WT_l,
                               const float* __restrict__ asrc_l,
                               const float* __restrict__ adst_l,
                               unsigned short* __restrict__ WhT_out,
                               float* __restrict__ srcv_out,
                               float* __restrict__ dstv_out,
                               int b, int n0t, int hh, int lane) {
    int rowLane = lane & 15, quad = lane >> 4;
    int bh = b * H + hh;
    const unsigned short* abase = hA_t + rowLane * 32 + quad * 8;
    const unsigned short* bbase = WT_l + (size_t)hh * 16384 + rowLane * 32 + quad * 8;
    f32x4 acc[4] = {};
#pragma unroll
    for (int kc = 0; kc < 8; ++kc) {
        short8 af = *(const short8*)(abase + kc * 512);
#pragma unroll
        for (int c = 0; c < 4; ++c) {
            short8 bf = *(const short8*)(bbase + (size_t)kc * 2048 + c * 512);
            acc[c] = __builtin_amdgcn_mfma_f32_16x16x32_bf16(af, bf, acc[c], 0, 0, 0);
        }
    }
    int m0 = n0t + quad * 4;
    float ps[4] = {0.f, 0.f, 0.f, 0.f}, pd[4] = {0.f, 0.f, 0.f, 0.f};
#pragma unroll
    for (int c = 0; c < 4; ++c) {
        int dh = c * 16 + rowLane;
        ushort4 o;
        o.x = f2bf(acc[c][0]); o.y = f2bf(acc[c][1]);
        o.z = f2bf(acc[c][2]); o.w = f2bf(acc[c][3]);
        *(ushort4*)&WhT_out[(((size_t)bh * 32 + (m0 >> 5)) * 64 + dh) * 32 + (m0 & 31)] = o;
        float as = asrc_l[hh * DH + dh];
        float ad = adst_l[hh * DH + dh];
#pragma unroll
        for (int r = 0; r < 4; ++r) { ps[r] += acc[c][r] * as; pd[r] += acc[c][r] * ad; }
    }
#pragma unroll
    for (int off = 1; off < 16; off <<= 1) {
#pragma unroll
        for (int r = 0; r < 4; ++r) {
            ps[r] += __shfl_xor(ps[r], off, 64);
            pd[r] += __shfl_xor(pd[r], off, 64);
        }
    }
    if (rowLane == 0) {
#pragma unroll
        for (int r = 0; r < 4; ++r) {
            srcv_out[bh * N + m0 + r] = ps[r];
            dstv_out[bh * N + m0 + r] = pd[r];
        }
    }
}

// ---- K2: blocks 0..511 gather/mean + layer-0 Wh ; blocks 512..1023 adjacency pack ----
__global__ __launch_bounds__(1024) void k_gp(const float* __restrict__ emb,
                                             const int* __restrict__ nodes,
                                             const int* __restrict__ adj,
                                             unsigned short* __restrict__ h_sw,
                                             unsigned long long* __restrict__ pack,
                                             const unsigned short* __restrict__ WT0,
                                             const float* __restrict__ asrc0,
                                             const float* __restrict__ adst0,
                                             unsigned short* __restrict__ WhT0,
                                             float* __restrict__ srcv0,
                                             float* __restrict__ dstv0) {
    int bt = blockIdx.x, tid = threadIdx.x;
    int wg = tid >> 6, lane = tid & 63;
    if (bt >= 512) {
        // ---- pack: 16 waves, wave = row ----
        int idx = bt - 512;
        int b = idx >> 6, n0 = (idx & 63) * 16;
        int n = n0 + wg;
        const int* arow = adj + ((size_t)(b * N + n)) * N;
        unsigned long long* prow = pack + ((size_t)(b * N + n)) * 16;
        int g16 = lane & 15;
#pragma unroll
        for (int it = 0; it < 4; ++it) {
            int m0 = it * 256 + lane * 4;
            int4 a = *(const int4*)(arow + m0);
            unsigned nib = (unsigned)((a.x != 0) || (m0 == n))
                         | ((unsigned)((a.y != 0) || (m0 + 1 == n)) << 1)
                         | ((unsigned)((a.z != 0) || (m0 + 2 == n)) << 2)
                         | ((unsigned)((a.w != 0) || (m0 + 3 == n)) << 3);
            unsigned long long v = (unsigned long long)nib << (g16 * 4);
            v |= __shfl_xor(v, 1, 64);
            v |= __shfl_xor(v, 2, 64);
            v |= __shfl_xor(v, 4, 64);
            v |= __shfl_xor(v, 8, 64);
            if (g16 == 0) prow[it * 4 + (lane >> 4)] = v;
        }
        return;
    }
    // ---- gather/mean -> h_sw + hA, then layer-0 Wh fused (waves 0..3 = heads) ----
    __shared__ __align__(16) int nodesLds[256];
    __shared__ __align__(16) unsigned short hA[8 * 16 * 32];
    int b = bt >> 6, nt = bt & 63, n0 = nt * 16;
    if (tid < 256) nodesLds[tid] = nodes[((size_t)(b * N + n0)) * L + tid];
    __syncthreads();
    int d4 = lane * 4;
    const int* np = nodesLds + wg * L;   // wave = row
    float4 s = make_float4(0.f, 0.f, 0.f, 0.f);
#pragma unroll
    for (int l = 0; l < L; ++l) {
        float4 v = *(const float4*)&emb[(size_t)np[l] * D + d4];
        s.x += v.x; s.y += v.y; s.z += v.z; s.w += v.w;
    }
    s.x *= (1.0f / L); s.y *= (1.0f / L); s.z *= (1.0f / L); s.w *= (1.0f / L);
    ushort4 o;
    o.x = f2bf(s.x); o.y = f2bf(s.y); o.z = f2bf(s.z); o.w = f2bf(s.w);
    int off = (d4 >> 5) * 512 + wg * 32 + (d4 & 31);
    *(ushort4*)&hA[off] = o;
    *(ushort4*)&h_sw[((size_t)(b * 64 + nt) * 8) * 512 + off] = o;
    __syncthreads();
    if (wg < 4) wh_tile(hA, WT0, asrc0, adst0, WhT0, srcv0, dstv0, b, n0, wg, lane);
}

// ---- K3/K4: attention, 8 waves = 4 heads x 2 m-halves; + LN (+ next-layer Wh) ----
// LDS plan:
// [0,16384)      dsts[4][1024] f32   (aliased by xt0 [0,17152) after sweep)
// [17408,34560)  xt1[16][268] f32
// [34560,36608)  packs[16][16] u64
// [36608,44800)  hA[8][16][32] bf16
// [44800,45312)  ssum[8][16] f32
#define AT_XT1  17408
#define AT_PACK 34560
#define AT_HA   36608
#define AT_SSUM 44800
#define AT_SIZE 45312

template <int FINAL>
__global__ __launch_bounds__(512, 4) void k_attn2(const unsigned long long* __restrict__ pack,
                                                  const float* __restrict__ srcv_in,
                                                  const float* __restrict__ dstv_in,
                                                  const unsigned short* __restrict__ WhT_in,
                                                  unsigned short* __restrict__ h_sw,
                                                  const float* __restrict__ scale_l,
                                                  const float* __restrict__ bias_l,
                                                  const unsigned short* __restrict__ WT_next,
                                                  const float* __restrict__ asrc_n,
                                                  const float* __restrict__ adst_n,
                                                  unsigned short* __restrict__ WhT_out,
                                                  float* __restrict__ srcv_out,
                                                  float* __restrict__ dstv_out,
                                                  float* __restrict__ out) {
    __shared__ __align__(16) char smem[AT_SIZE];
    float* dsts = (float*)smem;
    float* xt0 = (float*)smem;
    float* xt1 = (float*)(smem + AT_XT1);
    unsigned long long* packs = (unsigned long long*)(smem + AT_PACK);
    unsigned short* hA = (unsigned short*)(smem + AT_HA);
    float* ssum = (float*)(smem + AT_SSUM);

    int tid = threadIdx.x;
    int bt = blockIdx.x;
    int b = bt >> 6, nt = bt & 63, n0 = nt * 16;
    int wg = tid >> 6, lane = tid & 63;
    int half = wg >> 2, hh = wg & 3;
    int rowLane = lane & 15, quad = lane >> 4;
    int bh = b * H + hh;

    {   // dsts[hh][1024]: the two same-head waves load disjoint halves
        const float* dv = dstv_in + (size_t)bh * N + half * 512;
        *(float4*)(dsts + hh * 1024 + half * 512 + lane * 4) = *(const float4*)(dv + lane * 4);
        *(float4*)(dsts + hh * 1024 + half * 512 + 256 + lane * 4) = *(const float4*)(dv + 256 + lane * 4);
        if (tid < 256) packs[tid] = pack[((size_t)(b * N + n0 + (tid >> 4))) * 16 + (tid & 15)];
    }
    __syncthreads();

    float src = srcv_in[bh * N + n0 + rowLane];
    float mx = src > 0.f ? src : 0.2f * src;           // per-row shift, cancels in softmax
    const unsigned* prow = (const unsigned*)packs + rowLane * 32 + half * 16;
    const unsigned short* wbase = WhT_in + (size_t)bh * 65536 + rowLane * 32 + quad * 8;
    const float* dw = dsts + hh * 1024 + half * 512 + quad * 8;

    f32x4 acc[4] = {};
    float sum0 = 0.f, sum1 = 0.f;
    short8 fb[2][4];
#pragma unroll
    for (int c = 0; c < 4; ++c)
        fb[0][c] = *(const short8*)(wbase + (size_t)(half * 16) * 2048 + c * 512);
#pragma unroll 2
    for (int t2 = 0; t2 < 16; ++t2) {
        int cb = t2 & 1;
        int t2n = (t2 + 1) & 15;
#pragma unroll
        for (int c = 0; c < 4; ++c)
            fb[cb ^ 1][c] = *(const short8*)(wbase + (size_t)(half * 16 + t2n) * 2048 + c * 512);
        unsigned bits = (prow[t2] >> (quad * 8)) & 0xffu;
        float4 d0 = *(const float4*)(dw + t2 * 32);
        float4 d1 = *(const float4*)(dw + t2 * 32 + 4);
        float dd[8] = {d0.x, d0.y, d0.z, d0.w, d1.x, d1.y, d1.z, d1.w};
        unsigned pk[4];
#pragma unroll
        for (int j2 = 0; j2 < 4; ++j2) {
            float ea = src + dd[2 * j2];
            float eb = src + dd[2 * j2 + 1];
            ea = ea > 0.f ? ea : 0.2f * ea;
            eb = eb > 0.f ? eb : 0.2f * eb;
            float pa = ((bits >> (2 * j2)) & 1) ? __expf(ea - mx) : 0.f;
            float pb = ((bits >> (2 * j2 + 1)) & 1) ? __expf(eb - mx) : 0.f;
            sum0 += pa; sum1 += pb;
            pk[j2] = (__float_as_uint(pb) & 0xffff0000u) | (__float_as_uint(pa) >> 16);
        }
        U8 u; u.u = make_uint4(pk[0], pk[1], pk[2], pk[3]);
        short8 af = u.s;
        acc[0] = __builtin_amdgcn_mfma_f32_16x16x32_bf16(af, fb[cb][0], acc[0], 0, 0, 0);
        acc[1] = __builtin_amdgcn_mfma_f32_16x16x32_bf16(af, fb[cb][1], acc[1], 0, 0, 0);
        acc[2] = __builtin_amdgcn_mfma_f32_16x16x32_bf16(af, fb[cb][2], acc[2], 0, 0, 0);
        acc[3] = __builtin_amdgcn_mfma_f32_16x16x32_bf16(af, fb[cb][3], acc[3], 0, 0, 0);
    }
    // per-row partial sum for this half: sum across quads
    float sum = sum0 + sum1;
    sum += __shfl_xor(sum, 16, 64);
    sum += __shfl_xor(sum, 32, 64);
    if (quad == 0) ssum[wg * 16 + rowLane] = sum;
    __syncthreads();   // dsts reads done; ssum visible

    float inv[4];
#pragma unroll
    for (int r = 0; r < 4; ++r) {
        int rr = quad * 4 + r;
        inv[r] = 1.0f / (ssum[hh * 16 + rr] + ssum[(4 + hh) * 16 + rr]);
    }
    float* xtw = half ? xt1 : xt0;
#pragma unroll
    for (int c = 0; c < 4; ++c)
#pragma unroll
        for (int r = 0; r < 4; ++r)
            xtw[(quad * 4 + r) * 268 + hh * 64 + c * 16 + rowLane] = acc[c][r] * inv[r];
    __syncthreads();

    // ---- LN: 512 thr = (row = tid>>5, c8 = tid&31), 8 cols each ----
    int row = tid >> 5, c8 = tid & 31;
    int d0c = c8 * 8;
    size_t hsb = ((size_t)(b * 64 + nt) * 8 + (c8 >> 2)) * 512 + row * 32 + (c8 & 3) * 8;
    U8 r0;
    r0.u = *(const uint4*)(h_sw + hsb);
    float4 xa0 = *(const float4*)(xt0 + row * 268 + d0c);
    float4 xa1 = *(const float4*)(xt0 + row * 268 + d0c + 4);
    float4 xb0 = *(const float4*)(xt1 + row * 268 + d0c);
    float4 xb1 = *(const float4*)(xt1 + row * 268 + d0c + 4);
    float xp[8] = {xa0.x + xb0.x, xa0.y + xb0.y, xa0.z + xb0.z, xa0.w + xb0.w,
                   xa1.x + xb1.x, xa1.y + xb1.y, xa1.z + xb1.z, xa1.w + xb1.w};
    float xv[8];
    float s = 0.f, s2 = 0.f;
#pragma unroll
    for (int j = 0; j < 8; ++j) {
        float x = bf2f(((const unsigned short*)&r0)[j]) + xp[j];
        xv[j] = x; s += x; s2 += x * x;
    }
#pragma unroll
    for (int off = 1; off < 32; off <<= 1) {
        s += __shfl_xor(s, off, 32);
        s2 += __shfl_xor(s2, off, 32);
    }
    float mu = s * (1.0f / D);
    float var = s2 * (1.0f / D) - mu * mu;
    float rstd = rsqrtf(var + 1e-5f);
    if (FINAL) {
        float* orow = out + ((size_t)(b * N) + n0 + row) * D + d0c;
#pragma unroll
        for (int k = 0; k < 2; ++k) {
            float4 sc = *(const float4*)(scale_l + d0c + k * 4);
            float4 bi = *(const float4*)(bias_l + d0c + k * 4);
            float4 y;
            y.x = (xv[k * 4 + 0] - mu) * rstd * sc.x + bi.x;
            y.y = (xv[k * 4 + 1] - mu) * rstd * sc.y + bi.y;
            y.z = (xv[k * 4 + 2] - mu) * rstd * sc.z + bi.z;
            y.w = (xv[k * 4 + 3] - mu) * rstd * sc.w + bi.w;
            *(float4*)(orow + k * 4) = y;
        }
    } else {
        U8 o0;
#pragma unroll
        for (int j = 0; j < 8; ++j) {
            float scv = scale_l[d0c + j];
            float biv = bias_l[d0c + j];
            ((unsigned short*)&o0)[j] = f2bf((xv[j] - mu) * rstd * scv + biv);
        }
        *(uint4*)(h_sw + hsb) = o0.u;
        *(uint4*)&hA[(c8 >> 2) * 512 + row * 32 + (c8 & 3) * 8] = o0.u;
        __syncthreads();
        if (wg < 4)
            wh_tile(hA, WT_next, asrc_n, adst_n, WhT_out, srcv_out, dstv_out, b, n0, wg, lane);
    }
}

extern "C" void kernel_launch(void* const* d_in, const int* in_sizes, int n_in,
                              void* d_out, int out_size, void* d_ws, size_t ws_size,
                              hipStream_t stream) {
    const int* cfg_adj = (const int*)d_in[0];
    const int* cfg_nodes = (const int*)d_in[1];
    const int* cfg_len = (const int*)d_in[2];
    const float* emb = (const float*)d_in[3];
    const float* W = (const float*)d_in[4];
    const float* a_src = (const float*)d_in[5];
    const float* a_dst = (const float*)d_in[6];
    const float* ln_scale = (const float*)d_in[7];
    const float* ln_bias = (const float*)d_in[8];
    float* out = (float*)d_out;
    float* ws = (float*)d_ws;

    float* srcv0 = ws;
    float* dstv0 = srcv0 + (size_t)B * H * N;
    float* srcv1 = dstv0 + (size_t)B * H * N;
    float* dstv1 = srcv1 + (size_t)B * H * N;
    unsigned short* h_sw = (unsigned short*)(dstv1 + (size_t)B * H * N);
    unsigned short* WhT0 = h_sw + (size_t)B * N * D;
    unsigned short* WhT1 = WhT0 + (size_t)B * H * DH * N;
    unsigned short* WT_sw = WhT1 + (size_t)B * H * DH * N;   // both layers
    unsigned long long* pack = (unsigned long long*)(WT_sw + (size_t)NLAYERS * H * D * DH);

    k_pre<<<NLAYERS * H + 1, 1024, 0, stream>>>(W, cfg_len, WT_sw, out + (size_t)B * N * D);
    k_gp<<<1024, 1024, 0, stream>>>(emb, cfg_nodes, cfg_adj, h_sw, pack,
                                    WT_sw, a_src, a_dst, WhT0, srcv0, dstv0);
    k_attn2<0><<<512, 512, 0, stream>>>(pack, srcv0, dstv0, WhT0, h_sw,
                                        ln_scale, ln_bias,
                                        WT_sw + (size_t)H * 16384,
                                        a_src + (size_t)H * DH, a_dst + (size_t)H * DH,
                                        WhT1, srcv1, dstv1, nullptr);
    k_attn2<1><<<512, 512, 0, stream>>>(pack, srcv1, dstv1, WhT1, h_sw,
                                        ln_scale + D, ln_bias + D,
                                        nullptr, nullptr, nullptr,
                                        nullptr, nullptr, nullptr, out);
}

// Round 6
// 173.226 us; speedup vs baseline: 1.6693x; 1.0199x over previous
//
#include <hip/hip_runtime.h>
#include <math.h>

#define B 8
#define N 1024
#define L 16
#define D 256
#define H 4
#define DH 64
#define NLAYERS 2
#define V 32000

typedef __attribute__((ext_vector_type(8))) short short8;
typedef __attribute__((ext_vector_type(4))) float f32x4;

union U8 { uint4 u; short8 s; };

__device__ inline unsigned short f2bf(float x) {
    unsigned u = __float_as_uint(x);
    u = (u + 0x7fff + ((u >> 16) & 1)) >> 16;  // RNE
    return (unsigned short)u;
}
__device__ inline float bf2f(unsigned short x) {
    return __uint_as_float(((unsigned)x) << 16);
}

// -------- layouts --------
// h_sw  [b][n>>4][d>>5][n&15][d&31]  bf16  residual stream
// WT_sw [lh][d>>5][dh][d&31]         bf16  both layers (B operand of Wh MFMA)
// WhT   [bh][m>>5][dh][m&31]         bf16  (B operand of attn MFMA)
// pack  [b][n][m/64]                 u64 adjacency (+self-loop)
// emb_bf [v][d]                      bf16  pre-converted embedding table

#define CONV_THREADS 512000   // 500 blocks x 1024
#define CONV_F4      2048000  // V*D/4

// ---- K1: WT transpose (both layers) + len + emb fp32->bf16 conversion ----
__global__ __launch_bounds__(1024) void k_pre(const float* __restrict__ W,
                                              const int* __restrict__ len,
                                              const float* __restrict__ emb,
                                              unsigned short* __restrict__ WT_sw,
                                              unsigned short* __restrict__ emb_bf,
                                              float* __restrict__ out_len) {
    int bt = blockIdx.x, tid = threadIdx.x;
    if (bt < NLAYERS * H) {
        int lh = bt;
        const float* Wl = W + (size_t)lh * D * DH;
        int dh = tid & 63;
        int d0 = (tid >> 6) * 16;
#pragma unroll
        for (int i = 0; i < 16; ++i) {
            int d = d0 + i;
            WT_sw[(((size_t)lh * 8 + (d >> 5)) * 64 + dh) * 32 + (d & 31)] = f2bf(Wl[(size_t)d * DH + dh]);
        }
    } else if (bt == NLAYERS * H) {
        if (tid < B) out_len[tid] = (float)len[tid];
    } else {
        // emb conversion: 500 blocks x 1024 thr x 4 float4 (grid-strided, coalesced)
        int idx = (bt - NLAYERS * H - 1) * 1024 + tid;
        const float4* e4 = (const float4*)emb;
        ushort4* o4 = (ushort4*)emb_bf;
#pragma unroll
        for (int k = 0; k < 4; ++k) {
            int j = idx + k * CONV_THREADS;
            float4 v = e4[j];
            ushort4 o;
            o.x = f2bf(v.x); o.y = f2bf(v.y); o.z = f2bf(v.z); o.w = f2bf(v.w);
            o4[j] = o;
        }
    }
}

// ---- per-wave tile: Wh = h(16x256) @ W(head) from LDS/global WT, write WhT + srcv/dstv ----
__device__ inline void wh_tile(const unsigned short* hA_t,
                               const unsigned short* __restrict__ WT_l,
                               const float* __restrict__ asrc_l,
                               const float* __restrict__ adst_l,
                               unsigned short* __restrict__ WhT_out,
                               float* __restrict__ srcv_out,
                               float* __restrict__ dstv_out,
                               int b, int n0t, int hh, int lane) {
    int rowLane = lane & 15, quad = lane >> 4;
    int bh = b * H + hh;
    const unsigned short* abase = hA_t + rowLane * 32 + quad * 8;
    const unsigned short* bbase = WT_l + (size_t)hh * 16384 + rowLane * 32 + quad * 8;
    f32x4 acc[4] = {};
#pragma unroll
    for (int kc = 0; kc < 8; ++kc) {
        short8 af = *(const short8*)(abase + kc * 512);
#pragma unroll
        for (int c = 0; c < 4; ++c) {
            short8 bf = *(const short8*)(bbase + (size_t)kc * 2048 + c * 512);
            acc[c] = __builtin_amdgcn_mfma_f32_16x16x32_bf16(af, bf, acc[c], 0, 0, 0);
        }
    }
    int m0 = n0t + quad * 4;
    float ps[4] = {0.f, 0.f, 0.f, 0.f}, pd[4] = {0.f, 0.f, 0.f, 0.f};
#pragma unroll
    for (int c = 0; c < 4; ++c) {
        int dh = c * 16 + rowLane;
        ushort4 o;
        o.x = f2bf(acc[c][0]); o.y = f2bf(acc[c][1]);
        o.z = f2bf(acc[c][2]); o.w = f2bf(acc[c][3]);
        *(ushort4*)&WhT_out[(((size_t)bh * 32 + (m0 >> 5)) * 64 + dh) * 32 + (m0 & 31)] = o;
        float as = asrc_l[hh * DH + dh];
        float ad = adst_l[hh * DH + dh];
#pragma unroll
        for (int r = 0; r < 4; ++r) { ps[r] += acc[c][r] * as; pd[r] += acc[c][r] * ad; }
    }
#pragma unroll
    for (int off = 1; off < 16; off <<= 1) {
#pragma unroll
        for (int r = 0; r < 4; ++r) {
            ps[r] += __shfl_xor(ps[r], off, 64);
            pd[r] += __shfl_xor(pd[r], off, 64);
        }
    }
    if (rowLane == 0) {
#pragma unroll
        for (int r = 0; r < 4; ++r) {
            srcv_out[bh * N + m0 + r] = ps[r];
            dstv_out[bh * N + m0 + r] = pd[r];
        }
    }
}

// ---- K2: blocks 0..511 gather/mean (bf16 table) + layer-0 Wh ; blocks 512..1023 pack ----
__global__ __launch_bounds__(1024) void k_gp(const unsigned short* __restrict__ emb_bf,
                                             const int* __restrict__ nodes,
                                             const int* __restrict__ adj,
                                             unsigned short* __restrict__ h_sw,
                                             unsigned long long* __restrict__ pack,
                                             const unsigned short* __restrict__ WT0,
                                             const float* __restrict__ asrc0,
                                             const float* __restrict__ adst0,
                                             unsigned short* __restrict__ WhT0,
                                             float* __restrict__ srcv0,
                                             float* __restrict__ dstv0) {
    int bt = blockIdx.x, tid = threadIdx.x;
    int wg = tid >> 6, lane = tid & 63;
    if (bt >= 512) {
        // ---- pack: 16 waves, wave = row ----
        int idx = bt - 512;
        int b = idx >> 6, n0 = (idx & 63) * 16;
        int n = n0 + wg;
        const int* arow = adj + ((size_t)(b * N + n)) * N;
        unsigned long long* prow = pack + ((size_t)(b * N + n)) * 16;
        int g16 = lane & 15;
#pragma unroll
        for (int it = 0; it < 4; ++it) {
            int m0 = it * 256 + lane * 4;
            int4 a = *(const int4*)(arow + m0);
            unsigned nib = (unsigned)((a.x != 0) || (m0 == n))
                         | ((unsigned)((a.y != 0) || (m0 + 1 == n)) << 1)
                         | ((unsigned)((a.z != 0) || (m0 + 2 == n)) << 2)
                         | ((unsigned)((a.w != 0) || (m0 + 3 == n)) << 3);
            unsigned long long v = (unsigned long long)nib << (g16 * 4);
            v |= __shfl_xor(v, 1, 64);
            v |= __shfl_xor(v, 2, 64);
            v |= __shfl_xor(v, 4, 64);
            v |= __shfl_xor(v, 8, 64);
            if (g16 == 0) prow[it * 4 + (lane >> 4)] = v;
        }
        return;
    }
    // ---- gather/mean from bf16 table -> h_sw + hA, then layer-0 Wh (waves 0..3 = heads) ----
    __shared__ __align__(16) int nodesLds[256];
    __shared__ __align__(16) unsigned short hA[8 * 16 * 32];
    int b = bt >> 6, nt = bt & 63, n0 = nt * 16;
    if (tid < 256) nodesLds[tid] = nodes[((size_t)(b * N + n0)) * L + tid];
    __syncthreads();
    {
        int l32 = lane & 31, hi = lane >> 5;   // lane covers 8 cols; two tokens per pass
        int d8 = l32 * 8;
        const int* np = nodesLds + wg * L;     // wave = row
        float s[8] = {0.f, 0.f, 0.f, 0.f, 0.f, 0.f, 0.f, 0.f};
#pragma unroll
        for (int l = 0; l < 8; ++l) {
            int tok = np[l * 2 + hi];
            U8 v; v.u = *(const uint4*)&emb_bf[(size_t)tok * D + d8];
#pragma unroll
            for (int j = 0; j < 8; ++j) s[j] += bf2f(((const unsigned short*)&v)[j]);
        }
#pragma unroll
        for (int j = 0; j < 8; ++j) s[j] += __shfl_xor(s[j], 32, 64);
        if (hi == 0) {
            U8 o;
#pragma unroll
            for (int j = 0; j < 8; ++j) ((unsigned short*)&o)[j] = f2bf(s[j] * (1.0f / L));
            int off = (d8 >> 5) * 512 + wg * 32 + (d8 & 31);
            *(uint4*)&hA[off] = o.u;
            *(uint4*)&h_sw[((size_t)(b * 64 + nt) * 8) * 512 + off] = o.u;
        }
    }
    __syncthreads();
    if (wg < 4) wh_tile(hA, WT0, asrc0, adst0, WhT0, srcv0, dstv0, b, n0, wg, lane);
}

// ---- K3/K4: attention, 8 waves = 4 heads x 2 m-halves; + LN (+ next-layer Wh) ----
// LDS plan:
// [0,16384)      dsts[4][1024] f32   (aliased by xt0 [0,17152) after sweep)
// [17408,34560)  xt1[16][268] f32
// [34560,36608)  packs[16][16] u64
// [36608,44800)  hA[8][16][32] bf16
// [44800,45312)  ssum[8][16] f32
#define AT_XT1  17408
#define AT_PACK 34560
#define AT_HA   36608
#define AT_SSUM 44800
#define AT_SIZE 45312

template <int FINAL>
__global__ __launch_bounds__(512, 4) void k_attn2(const unsigned long long* __restrict__ pack,
                                                  const float* __restrict__ srcv_in,
                                                  const float* __restrict__ dstv_in,
                                                  const unsigned short* __restrict__ WhT_in,
                                                  unsigned short* __restrict__ h_sw,
                                                  const float* __restrict__ scale_l,
                                                  const float* __restrict__ bias_l,
                                                  const unsigned short* __restrict__ WT_next,
                                                  const float* __restrict__ asrc_n,
                                                  const float* __restrict__ adst_n,
                                                  unsigned short* __restrict__ WhT_out,
                                                  float* __restrict__ srcv_out,
                                                  float* __restrict__ dstv_out,
                                                  float* __restrict__ out) {
    __shared__ __align__(16) char smem[AT_SIZE];
    float* dsts = (float*)smem;
    float* xt0 = (float*)smem;
    float* xt1 = (float*)(smem + AT_XT1);
    unsigned long long* packs = (unsigned long long*)(smem + AT_PACK);
    unsigned short* hA = (unsigned short*)(smem + AT_HA);
    float* ssum = (float*)(smem + AT_SSUM);

    int tid = threadIdx.x;
    int bt = blockIdx.x;
    int b = bt >> 6, nt = bt & 63, n0 = nt * 16;
    int wg = tid >> 6, lane = tid & 63;
    int half = wg >> 2, hh = wg & 3;
    int rowLane = lane & 15, quad = lane >> 4;
    int bh = b * H + hh;

    {   // dsts[hh][1024]: the two same-head waves load disjoint halves
        const float* dv = dstv_in + (size_t)bh * N + half * 512;
        *(float4*)(dsts + hh * 1024 + half * 512 + lane * 4) = *(const float4*)(dv + lane * 4);
        *(float4*)(dsts + hh * 1024 + half * 512 + 256 + lane * 4) = *(const float4*)(dv + 256 + lane * 4);
        if (tid < 256) packs[tid] = pack[((size_t)(b * N + n0 + (tid >> 4))) * 16 + (tid & 15)];
    }
    __syncthreads();

    float src = srcv_in[bh * N + n0 + rowLane];
    float mx = src > 0.f ? src : 0.2f * src;           // per-row shift, cancels in softmax
    const unsigned* prow = (const unsigned*)packs + rowLane * 32 + half * 16;
    const unsigned short* wbase = WhT_in + (size_t)bh * 65536 + rowLane * 32 + quad * 8;
    const float* dw = dsts + hh * 1024 + half * 512 + quad * 8;

    f32x4 acc[4] = {};
    float sum0 = 0.f, sum1 = 0.f;
    short8 fb[2][4];
#pragma unroll
    for (int c = 0; c < 4; ++c)
        fb[0][c] = *(const short8*)(wbase + (size_t)(half * 16) * 2048 + c * 512);
#pragma unroll 2
    for (int t2 = 0; t2 < 16; ++t2) {
        int cb = t2 & 1;
        int t2n = (t2 + 1) & 15;
#pragma unroll
        for (int c = 0; c < 4; ++c)
            fb[cb ^ 1][c] = *(const short8*)(wbase + (size_t)(half * 16 + t2n) * 2048 + c * 512);
        unsigned bits = (prow[t2] >> (quad * 8)) & 0xffu;
        float4 d0 = *(const float4*)(dw + t2 * 32);
        float4 d1 = *(const float4*)(dw + t2 * 32 + 4);
        float dd[8] = {d0.x, d0.y, d0.z, d0.w, d1.x, d1.y, d1.z, d1.w};
        unsigned pk[4];
#pragma unroll
        for (int j2 = 0; j2 < 4; ++j2) {
            float ea = src + dd[2 * j2];
            float eb = src + dd[2 * j2 + 1];
            ea = ea > 0.f ? ea : 0.2f * ea;
            eb = eb > 0.f ? eb : 0.2f * eb;
            float pa = ((bits >> (2 * j2)) & 1) ? __expf(ea - mx) : 0.f;
            float pb = ((bits >> (2 * j2 + 1)) & 1) ? __expf(eb - mx) : 0.f;
            sum0 += pa; sum1 += pb;
            pk[j2] = (__float_as_uint(pb) & 0xffff0000u) | (__float_as_uint(pa) >> 16);
        }
        U8 u; u.u = make_uint4(pk[0], pk[1], pk[2], pk[3]);
        short8 af = u.s;
        acc[0] = __builtin_amdgcn_mfma_f32_16x16x32_bf16(af, fb[cb][0], acc[0], 0, 0, 0);
        acc[1] = __builtin_amdgcn_mfma_f32_16x16x32_bf16(af, fb[cb][1], acc[1], 0, 0, 0);
        acc[2] = __builtin_amdgcn_mfma_f32_16x16x32_bf16(af, fb[cb][2], acc[2], 0, 0, 0);
        acc[3] = __builtin_amdgcn_mfma_f32_16x16x32_bf16(af, fb[cb][3], acc[3], 0, 0, 0);
    }
    // per-row partial sum for this half: sum across quads
    float sum = sum0 + sum1;
    sum += __shfl_xor(sum, 16, 64);
    sum += __shfl_xor(sum, 32, 64);
    if (quad == 0) ssum[wg * 16 + rowLane] = sum;
    __syncthreads();   // dsts reads done; ssum visible

    float inv[4];
#pragma unroll
    for (int r = 0; r < 4; ++r) {
        int rr = quad * 4 + r;
        inv[r] = 1.0f / (ssum[hh * 16 + rr] + ssum[(4 + hh) * 16 + rr]);
    }
    float* xtw = half ? xt1 : xt0;
#pragma unroll
    for (int c = 0; c < 4; ++c)
#pragma unroll
        for (int r = 0; r < 4; ++r)
            xtw[(quad * 4 + r) * 268 + hh * 64 + c * 16 + rowLane] = acc[c][r] * inv[r];
    __syncthreads();

    // ---- LN: 512 thr = (row = tid>>5, c8 = tid&31), 8 cols each ----
    int row = tid >> 5, c8 = tid & 31;
    int d0c = c8 * 8;
    size_t hsb = ((size_t)(b * 64 + nt) * 8 + (c8 >> 2)) * 512 + row * 32 + (c8 & 3) * 8;
    U8 r0;
    r0.u = *(const uint4*)(h_sw + hsb);
    float4 xa0 = *(const float4*)(xt0 + row * 268 + d0c);
    float4 xa1 = *(const float4*)(xt0 + row * 268 + d0c + 4);
    float4 xb0 = *(const float4*)(xt1 + row * 268 + d0c);
    float4 xb1 = *(const float4*)(xt1 + row * 268 + d0c + 4);
    float xp[8] = {xa0.x + xb0.x, xa0.y + xb0.y, xa0.z + xb0.z, xa0.w + xb0.w,
                   xa1.x + xb1.x, xa1.y + xb1.y, xa1.z + xb1.z, xa1.w + xb1.w};
    float xv[8];
    float s = 0.f, s2 = 0.f;
#pragma unroll
    for (int j = 0; j < 8; ++j) {
        float x = bf2f(((const unsigned short*)&r0)[j]) + xp[j];
        xv[j] = x; s += x; s2 += x * x;
    }
#pragma unroll
    for (int off = 1; off < 32; off <<= 1) {
        s += __shfl_xor(s, off, 32);
        s2 += __shfl_xor(s2, off, 32);
    }
    float mu = s * (1.0f / D);
    float var = s2 * (1.0f / D) - mu * mu;
    float rstd = rsqrtf(var + 1e-5f);
    if (FINAL) {
        float* orow = out + ((size_t)(b * N) + n0 + row) * D + d0c;
#pragma unroll
        for (int k = 0; k < 2; ++k) {
            float4 sc = *(const float4*)(scale_l + d0c + k * 4);
            float4 bi = *(const float4*)(bias_l + d0c + k * 4);
            float4 y;
            y.x = (xv[k * 4 + 0] - mu) * rstd * sc.x + bi.x;
            y.y = (xv[k * 4 + 1] - mu) * rstd * sc.y + bi.y;
            y.z = (xv[k * 4 + 2] - mu) * rstd * sc.z + bi.z;
            y.w = (xv[k * 4 + 3] - mu) * rstd * sc.w + bi.w;
            *(float4*)(orow + k * 4) = y;
        }
    } else {
        U8 o0;
#pragma unroll
        for (int j = 0; j < 8; ++j) {
            float scv = scale_l[d0c + j];
            float biv = bias_l[d0c + j];
            ((unsigned short*)&o0)[j] = f2bf((xv[j] - mu) * rstd * scv + biv);
        }
        *(uint4*)(h_sw + hsb) = o0.u;
        *(uint4*)&hA[(c8 >> 2) * 512 + row * 32 + (c8 & 3) * 8] = o0.u;
        __syncthreads();
        if (wg < 4)
            wh_tile(hA, WT_next, asrc_n, adst_n, WhT_out, srcv_out, dstv_out, b, n0, wg, lane);
    }
}

extern "C" void kernel_launch(void* const* d_in, const int* in_sizes, int n_in,
                              void* d_out, int out_size, void* d_ws, size_t ws_size,
                              hipStream_t stream) {
    const int* cfg_adj = (const int*)d_in[0];
    const int* cfg_nodes = (const int*)d_in[1];
    const int* cfg_len = (const int*)d_in[2];
    const float* emb = (const float*)d_in[3];
    const float* W = (const float*)d_in[4];
    const float* a_src = (const float*)d_in[5];
    const float* a_dst = (const float*)d_in[6];
    const float* ln_scale = (const float*)d_in[7];
    const float* ln_bias = (const float*)d_in[8];
    float* out = (float*)d_out;
    float* ws = (float*)d_ws;

    float* srcv0 = ws;
    float* dstv0 = srcv0 + (size_t)B * H * N;
    float* srcv1 = dstv0 + (size_t)B * H * N;
    float* dstv1 = srcv1 + (size_t)B * H * N;
    unsigned short* h_sw = (unsigned short*)(dstv1 + (size_t)B * H * N);
    unsigned short* WhT0 = h_sw + (size_t)B * N * D;
    unsigned short* WhT1 = WhT0 + (size_t)B * H * DH * N;
    unsigned short* WT_sw = WhT1 + (size_t)B * H * DH * N;   // both layers
    unsigned long long* pack = (unsigned long long*)(WT_sw + (size_t)NLAYERS * H * D * DH);
    unsigned short* emb_bf = (unsigned short*)(pack + (size_t)B * N * 16);

    k_pre<<<NLAYERS * H + 1 + 500, 1024, 0, stream>>>(W, cfg_len, emb, WT_sw, emb_bf,
                                                      out + (size_t)B * N * D);
    k_gp<<<1024, 1024, 0, stream>>>(emb_bf, cfg_nodes, cfg_adj, h_sw, pack,
                                    WT_sw, a_src, a_dst, WhT0, srcv0, dstv0);
    k_attn2<0><<<512, 512, 0, stream>>>(pack, srcv0, dstv0, WhT0, h_sw,
                                        ln_scale, ln_bias,
                                        WT_sw + (size_t)H * 16384,
                                        a_src + (size_t)H * DH, a_dst + (size_t)H * DH,
                                        WhT1, srcv1, dstv1, nullptr);
    k_attn2<1><<<512, 512, 0, stream>>>(pack, srcv1, dstv1, WhT1, h_sw,
                                        ln_scale + D, ln_bias + D,
                                        nullptr, nullptr, nullptr,
                                        nullptr, nullptr, nullptr, out);
}

// Round 7
// 173.053 us; speedup vs baseline: 1.6710x; 1.0010x over previous
//
#include <hip/hip_runtime.h>
#include <math.h>

#define B 8
#define N 1024
#define L 16
#define D 256
#define H 4
#define DH 64
#define NLAYERS 2
#define V 32000

typedef __attribute__((ext_vector_type(8))) short short8;
typedef __attribute__((ext_vector_type(4))) float f32x4;

union U8 { uint4 u; short8 s; };

__device__ inline unsigned short f2bf(float x) {
    unsigned u = __float_as_uint(x);
    u = (u + 0x7fff + ((u >> 16) & 1)) >> 16;  // RNE
    return (unsigned short)u;
}
__device__ inline float bf2f(unsigned short x) {
    return __uint_as_float(((unsigned)x) << 16);
}

// -------- layouts --------
// h_sw  [b][n>>4][d>>5][n&15][d&31]  bf16  residual stream
// WT_sw [lh][d>>5][dh][d&31]         bf16  both layers (B operand of Wh MFMA)
// WhT   [bh][m>>5][dh][m&31]         bf16  (B operand of attn MFMA)
// pack  [b][n][m/64]                 u64 adjacency (+self-loop)
// emb_bf [v][d]                      bf16  pre-converted embedding table

#define CONV_THREADS 512000   // 500 blocks x 1024
#define CONV_F4      2048000  // V*D/4

// ---- K1: WT transpose (both layers) + len + emb fp32->bf16 conversion ----
__global__ __launch_bounds__(1024) void k_pre(const float* __restrict__ W,
                                              const int* __restrict__ len,
                                              const float* __restrict__ emb,
                                              unsigned short* __restrict__ WT_sw,
                                              unsigned short* __restrict__ emb_bf,
                                              float* __restrict__ out_len) {
    int bt = blockIdx.x, tid = threadIdx.x;
    if (bt < NLAYERS * H) {
        int lh = bt;
        const float* Wl = W + (size_t)lh * D * DH;
        int dh = tid & 63;
        int d0 = (tid >> 6) * 16;
#pragma unroll
        for (int i = 0; i < 16; ++i) {
            int d = d0 + i;
            WT_sw[(((size_t)lh * 8 + (d >> 5)) * 64 + dh) * 32 + (d & 31)] = f2bf(Wl[(size_t)d * DH + dh]);
        }
    } else if (bt == NLAYERS * H) {
        if (tid < B) out_len[tid] = (float)len[tid];
    } else {
        // emb conversion: 500 blocks x 1024 thr x 4 float4 (grid-strided, coalesced)
        int idx = (bt - NLAYERS * H - 1) * 1024 + tid;
        const float4* e4 = (const float4*)emb;
        ushort4* o4 = (ushort4*)emb_bf;
#pragma unroll
        for (int k = 0; k < 4; ++k) {
            int j = idx + k * CONV_THREADS;
            float4 v = e4[j];
            ushort4 o;
            o.x = f2bf(v.x); o.y = f2bf(v.y); o.z = f2bf(v.z); o.w = f2bf(v.w);
            o4[j] = o;
        }
    }
}

// ---- per-wave tile: Wh = h(16x256) @ W(head), write WhT + srcv/dstv ----
__device__ inline void wh_tile(const unsigned short* hA_t,
                               const unsigned short* __restrict__ WT_l,
                               const float* __restrict__ asrc_l,
                               const float* __restrict__ adst_l,
                               unsigned short* __restrict__ WhT_out,
                               float* __restrict__ srcv_out,
                               float* __restrict__ dstv_out,
                               int b, int n0t, int hh, int lane) {
    int rowLane = lane & 15, quad = lane >> 4;
    int bh = b * H + hh;
    const unsigned short* abase = hA_t + rowLane * 32 + quad * 8;
    const unsigned short* bbase = WT_l + (size_t)hh * 16384 + rowLane * 32 + quad * 8;
    f32x4 acc[4] = {};
#pragma unroll
    for (int kc = 0; kc < 8; ++kc) {
        short8 af = *(const short8*)(abase + kc * 512);
#pragma unroll
        for (int c = 0; c < 4; ++c) {
            short8 bf = *(const short8*)(bbase + (size_t)kc * 2048 + c * 512);
            acc[c] = __builtin_amdgcn_mfma_f32_16x16x32_bf16(af, bf, acc[c], 0, 0, 0);
        }
    }
    int m0 = n0t + quad * 4;
    float ps[4] = {0.f, 0.f, 0.f, 0.f}, pd[4] = {0.f, 0.f, 0.f, 0.f};
#pragma unroll
    for (int c = 0; c < 4; ++c) {
        int dh = c * 16 + rowLane;
        ushort4 o;
        o.x = f2bf(acc[c][0]); o.y = f2bf(acc[c][1]);
        o.z = f2bf(acc[c][2]); o.w = f2bf(acc[c][3]);
        *(ushort4*)&WhT_out[(((size_t)bh * 32 + (m0 >> 5)) * 64 + dh) * 32 + (m0 & 31)] = o;
        float as = asrc_l[hh * DH + dh];
        float ad = adst_l[hh * DH + dh];
#pragma unroll
        for (int r = 0; r < 4; ++r) { ps[r] += acc[c][r] * as; pd[r] += acc[c][r] * ad; }
    }
#pragma unroll
    for (int off = 1; off < 16; off <<= 1) {
#pragma unroll
        for (int r = 0; r < 4; ++r) {
            ps[r] += __shfl_xor(ps[r], off, 64);
            pd[r] += __shfl_xor(pd[r], off, 64);
        }
    }
    if (rowLane == 0) {
#pragma unroll
        for (int r = 0; r < 4; ++r) {
            srcv_out[bh * N + m0 + r] = ps[r];
            dstv_out[bh * N + m0 + r] = pd[r];
        }
    }
}

// ---- K2: blocks 0..511 gather/mean (bf16 table) + layer-0 Wh ; blocks 512..1023 pack ----
__global__ __launch_bounds__(1024) void k_gp(const unsigned short* __restrict__ emb_bf,
                                             const int* __restrict__ nodes,
                                             const int* __restrict__ adj,
                                             unsigned short* __restrict__ h_sw,
                                             unsigned long long* __restrict__ pack,
                                             const unsigned short* __restrict__ WT0,
                                             const float* __restrict__ asrc0,
                                             const float* __restrict__ adst0,
                                             unsigned short* __restrict__ WhT0,
                                             float* __restrict__ srcv0,
                                             float* __restrict__ dstv0) {
    int bt = blockIdx.x, tid = threadIdx.x;
    int wg = tid >> 6, lane = tid & 63;
    if (bt >= 512) {
        // ---- pack: 16 waves, wave = row ----
        int idx = bt - 512;
        int b = idx >> 6, n0 = (idx & 63) * 16;
        int n = n0 + wg;
        const int* arow = adj + ((size_t)(b * N + n)) * N;
        unsigned long long* prow = pack + ((size_t)(b * N + n)) * 16;
        int g16 = lane & 15;
#pragma unroll
        for (int it = 0; it < 4; ++it) {
            int m0 = it * 256 + lane * 4;
            int4 a = *(const int4*)(arow + m0);
            unsigned nib = (unsigned)((a.x != 0) || (m0 == n))
                         | ((unsigned)((a.y != 0) || (m0 + 1 == n)) << 1)
                         | ((unsigned)((a.z != 0) || (m0 + 2 == n)) << 2)
                         | ((unsigned)((a.w != 0) || (m0 + 3 == n)) << 3);
            unsigned long long v = (unsigned long long)nib << (g16 * 4);
            v |= __shfl_xor(v, 1, 64);
            v |= __shfl_xor(v, 2, 64);
            v |= __shfl_xor(v, 4, 64);
            v |= __shfl_xor(v, 8, 64);
            if (g16 == 0) prow[it * 4 + (lane >> 4)] = v;
        }
        return;
    }
    // ---- gather/mean from bf16 table -> h_sw + hA, then layer-0 Wh (waves 0..3 = heads) ----
    __shared__ __align__(16) int nodesLds[256];
    __shared__ __align__(16) unsigned short hA[8 * 16 * 32];
    int b = bt >> 6, nt = bt & 63, n0 = nt * 16;
    if (tid < 256) nodesLds[tid] = nodes[((size_t)(b * N + n0)) * L + tid];
    __syncthreads();
    {
        int l32 = lane & 31, hi = lane >> 5;   // lane covers 8 cols; two tokens per pass
        int d8 = l32 * 8;
        const int* np = nodesLds + wg * L;     // wave = row
        float s[8] = {0.f, 0.f, 0.f, 0.f, 0.f, 0.f, 0.f, 0.f};
#pragma unroll
        for (int l = 0; l < 8; ++l) {
            int tok = np[l * 2 + hi];
            U8 v; v.u = *(const uint4*)&emb_bf[(size_t)tok * D + d8];
#pragma unroll
            for (int j = 0; j < 8; ++j) s[j] += bf2f(((const unsigned short*)&v)[j]);
        }
#pragma unroll
        for (int j = 0; j < 8; ++j) s[j] += __shfl_xor(s[j], 32, 64);
        if (hi == 0) {
            U8 o;
#pragma unroll
            for (int j = 0; j < 8; ++j) ((unsigned short*)&o)[j] = f2bf(s[j] * (1.0f / L));
            int off = (d8 >> 5) * 512 + wg * 32 + (d8 & 31);
            *(uint4*)&hA[off] = o.u;
            *(uint4*)&h_sw[((size_t)(b * 64 + nt) * 8) * 512 + off] = o.u;
        }
    }
    __syncthreads();
    if (wg < 4) wh_tile(hA, WT0, asrc0, adst0, WhT0, srcv0, dstv0, b, n0, wg, lane);
}

// ---- K3/K4: attention, 256 blocks (XCD-affine b = bt&7) x 512 thr.
//      8 waves = 2 row-tiles x 4 heads; each wave sweeps full m. + LN (+ next Wh) ----
// LDS plan:
// [0,34304)      xt[2][16][268] f32  (xt0 aliases dsts[4][1024] f32 in [0,16384))
// [34304,38400)  packs[32][16] u64
// [38400,46592)  hA[2][8][16][32] bf16
#define A3_PACK 34304
#define A3_HA   38400
#define A3_SIZE 46592

template <int FINAL>
__global__ __launch_bounds__(512, 2) void k_attn3(const unsigned long long* __restrict__ pack,
                                                  const float* __restrict__ srcv_in,
                                                  const float* __restrict__ dstv_in,
                                                  const unsigned short* __restrict__ WhT_in,
                                                  unsigned short* __restrict__ h_sw,
                                                  const float* __restrict__ scale_l,
                                                  const float* __restrict__ bias_l,
                                                  const unsigned short* __restrict__ WT_next,
                                                  const float* __restrict__ asrc_n,
                                                  const float* __restrict__ adst_n,
                                                  unsigned short* __restrict__ WhT_out,
                                                  float* __restrict__ srcv_out,
                                                  float* __restrict__ dstv_out,
                                                  float* __restrict__ out) {
    __shared__ __align__(16) char smem[A3_SIZE];
    float* dsts = (float*)smem;
    unsigned long long* packs = (unsigned long long*)(smem + A3_PACK);
    unsigned short* hAall = (unsigned short*)(smem + A3_HA);

    int tid = threadIdx.x;
    int bt = blockIdx.x;
    int b = bt & 7, pr = bt >> 3;          // XCD-affine: all blocks of batch b on one XCD
    int n0base = pr * 32;
    int wg = tid >> 6, lane = tid & 63;
    int tg = wg >> 2, hh = wg & 3;         // tile-group, head
    int rowLane = lane & 15, quad = lane >> 4;
    int bh = b * H + hh;
    int n0t = n0base + tg * 16;

    {   // dsts[hh][1024]: the two same-head waves load disjoint halves
        const float* dv = dstv_in + (size_t)bh * N + tg * 512;
        *(float4*)(dsts + hh * 1024 + tg * 512 + lane * 4) = *(const float4*)(dv + lane * 4);
        *(float4*)(dsts + hh * 1024 + tg * 512 + 256 + lane * 4) = *(const float4*)(dv + 256 + lane * 4);
        packs[tid] = pack[((size_t)(b * N + n0base + (tid >> 4))) * 16 + (tid & 15)];
    }
    __syncthreads();

    float src = srcv_in[bh * N + n0t + rowLane];
    float mx = src > 0.f ? src : 0.2f * src;           // per-row shift, cancels in softmax
    const unsigned* prow = (const unsigned*)packs + (tg * 16 + rowLane) * 32;
    const unsigned short* wbase = WhT_in + (size_t)bh * 65536 + rowLane * 32 + quad * 8;
    const float* dw = dsts + hh * 1024 + quad * 8;

    f32x4 acc[4] = {};
    float sum0 = 0.f, sum1 = 0.f;
    short8 fb[2][4];
#pragma unroll
    for (int c = 0; c < 4; ++c) fb[0][c] = *(const short8*)(wbase + c * 512);
#pragma unroll 2
    for (int t2 = 0; t2 < 32; ++t2) {
        int cb = t2 & 1;
        int t2n = (t2 + 1) & 31;
#pragma unroll
        for (int c = 0; c < 4; ++c)
            fb[cb ^ 1][c] = *(const short8*)(wbase + (size_t)t2n * 2048 + c * 512);
        unsigned bits = (prow[t2] >> (quad * 8)) & 0xffu;
        float4 d0 = *(const float4*)(dw + t2 * 32);
        float4 d1 = *(const float4*)(dw + t2 * 32 + 4);
        float dd[8] = {d0.x, d0.y, d0.z, d0.w, d1.x, d1.y, d1.z, d1.w};
        unsigned pk[4];
#pragma unroll
        for (int j2 = 0; j2 < 4; ++j2) {
            float ea = src + dd[2 * j2];
            float eb = src + dd[2 * j2 + 1];
            ea = ea > 0.f ? ea : 0.2f * ea;
            eb = eb > 0.f ? eb : 0.2f * eb;
            float pa = ((bits >> (2 * j2)) & 1) ? __expf(ea - mx) : 0.f;
            float pb = ((bits >> (2 * j2 + 1)) & 1) ? __expf(eb - mx) : 0.f;
            sum0 += pa; sum1 += pb;
            pk[j2] = (__float_as_uint(pb) & 0xffff0000u) | (__float_as_uint(pa) >> 16);
        }
        U8 u; u.u = make_uint4(pk[0], pk[1], pk[2], pk[3]);
        short8 af = u.s;
        acc[0] = __builtin_amdgcn_mfma_f32_16x16x32_bf16(af, fb[cb][0], acc[0], 0, 0, 0);
        acc[1] = __builtin_amdgcn_mfma_f32_16x16x32_bf16(af, fb[cb][1], acc[1], 0, 0, 0);
        acc[2] = __builtin_amdgcn_mfma_f32_16x16x32_bf16(af, fb[cb][2], acc[2], 0, 0, 0);
        acc[3] = __builtin_amdgcn_mfma_f32_16x16x32_bf16(af, fb[cb][3], acc[3], 0, 0, 0);
    }
    // full row sums in-wave
    float sum = sum0 + sum1;
    sum += __shfl_xor(sum, 16, 64);
    sum += __shfl_xor(sum, 32, 64);
    float inv[4];
#pragma unroll
    for (int r = 0; r < 4; ++r) inv[r] = 1.0f / __shfl(sum, quad * 4 + r, 64);

    __syncthreads();   // all waves done reading dsts before xt overwrite
    float* xtw = (float*)smem + tg * 4288;
#pragma unroll
    for (int c = 0; c < 4; ++c)
#pragma unroll
        for (int r = 0; r < 4; ++r)
            xtw[(quad * 4 + r) * 268 + hh * 64 + c * 16 + rowLane] = acc[c][r] * inv[r];
    __syncthreads();

    // ---- LN: 512 thr = 2 tiles x (row, g = col-group of 16) ----
    int tg2 = tid >> 8, rowg = tid & 255;
    int row = rowg >> 4, g = rowg & 15;
    int nt = pr * 2 + tg2;
    const float* xtt = (float*)smem + tg2 * 4288;
    size_t hsb = ((size_t)(b * 64 + nt) * 8 + (g >> 1)) * 512 + row * 32 + (g & 1) * 16;
    U8 r0, r1;
    r0.u = *(const uint4*)(h_sw + hsb);
    r1.u = *(const uint4*)(h_sw + hsb + 8);
    float4 xr[4];
#pragma unroll
    for (int k = 0; k < 4; ++k) xr[k] = *(const float4*)(xtt + row * 268 + g * 16 + k * 4);
    float xv[16];
    float s = 0.f, s2 = 0.f;
#pragma unroll
    for (int j = 0; j < 16; ++j) {
        unsigned short hv = (j < 8) ? ((const unsigned short*)&r0)[j] : ((const unsigned short*)&r1)[j - 8];
        float x = bf2f(hv) + ((const float*)xr)[j];
        xv[j] = x; s += x; s2 += x * x;
    }
#pragma unroll
    for (int off = 1; off < 16; off <<= 1) {
        s += __shfl_xor(s, off, 64);
        s2 += __shfl_xor(s2, off, 64);
    }
    float mu = s * (1.0f / D);
    float var = s2 * (1.0f / D) - mu * mu;
    float rstd = rsqrtf(var + 1e-5f);
    int d0c = g * 16;
    if (FINAL) {
        float* orow = out + ((size_t)(b * N) + nt * 16 + row) * D + d0c;
#pragma unroll
        for (int k = 0; k < 4; ++k) {
            float4 sc = *(const float4*)(scale_l + d0c + k * 4);
            float4 bi = *(const float4*)(bias_l + d0c + k * 4);
            float4 y;
            y.x = (xv[k * 4 + 0] - mu) * rstd * sc.x + bi.x;
            y.y = (xv[k * 4 + 1] - mu) * rstd * sc.y + bi.y;
            y.z = (xv[k * 4 + 2] - mu) * rstd * sc.z + bi.z;
            y.w = (xv[k * 4 + 3] - mu) * rstd * sc.w + bi.w;
            *(float4*)(orow + k * 4) = y;
        }
    } else {
        U8 o0, o1;
#pragma unroll
        for (int j = 0; j < 16; ++j) {
            float scv = scale_l[d0c + j];
            float biv = bias_l[d0c + j];
            unsigned short yb = f2bf((xv[j] - mu) * rstd * scv + biv);
            if (j < 8) ((unsigned short*)&o0)[j] = yb;
            else ((unsigned short*)&o1)[j - 8] = yb;
        }
        *(uint4*)(h_sw + hsb) = o0.u;
        *(uint4*)(h_sw + hsb + 8) = o1.u;
        unsigned short* ha = hAall + tg2 * 4096 + (g >> 1) * 512 + row * 32 + (g & 1) * 16;
        *(uint4*)ha = o0.u;
        *(uint4*)(ha + 8) = o1.u;
        __syncthreads();
        // all 8 waves: (tile tg, head hh)
        wh_tile(hAall + tg * 4096, WT_next, asrc_n, adst_n, WhT_out, srcv_out, dstv_out,
                b, n0t, hh, lane);
    }
}

extern "C" void kernel_launch(void* const* d_in, const int* in_sizes, int n_in,
                              void* d_out, int out_size, void* d_ws, size_t ws_size,
                              hipStream_t stream) {
    const int* cfg_adj = (const int*)d_in[0];
    const int* cfg_nodes = (const int*)d_in[1];
    const int* cfg_len = (const int*)d_in[2];
    const float* emb = (const float*)d_in[3];
    const float* W = (const float*)d_in[4];
    const float* a_src = (const float*)d_in[5];
    const float* a_dst = (const float*)d_in[6];
    const float* ln_scale = (const float*)d_in[7];
    const float* ln_bias = (const float*)d_in[8];
    float* out = (float*)d_out;
    float* ws = (float*)d_ws;

    float* srcv0 = ws;
    float* dstv0 = srcv0 + (size_t)B * H * N;
    float* srcv1 = dstv0 + (size_t)B * H * N;
    float* dstv1 = srcv1 + (size_t)B * H * N;
    unsigned short* h_sw = (unsigned short*)(dstv1 + (size_t)B * H * N);
    unsigned short* WhT0 = h_sw + (size_t)B * N * D;
    unsigned short* WhT1 = WhT0 + (size_t)B * H * DH * N;
    unsigned short* WT_sw = WhT1 + (size_t)B * H * DH * N;   // both layers
    unsigned long long* pack = (unsigned long long*)(WT_sw + (size_t)NLAYERS * H * D * DH);
    unsigned short* emb_bf = (unsigned short*)(pack + (size_t)B * N * 16);

    k_pre<<<NLAYERS * H + 1 + 500, 1024, 0, stream>>>(W, cfg_len, emb, WT_sw, emb_bf,
                                                      out + (size_t)B * N * D);
    k_gp<<<1024, 1024, 0, stream>>>(emb_bf, cfg_nodes, cfg_adj, h_sw, pack,
                                    WT_sw, a_src, a_dst, WhT0, srcv0, dstv0);
    k_attn3<0><<<256, 512, 0, stream>>>(pack, srcv0, dstv0, WhT0, h_sw,
                                        ln_scale, ln_bias,
                                        WT_sw + (size_t)H * 16384,
                                        a_src + (size_t)H * DH, a_dst + (size_t)H * DH,
                                        WhT1, srcv1, dstv1, nullptr);
    k_attn3<1><<<256, 512, 0, stream>>>(pack, srcv1, dstv1, WhT1, h_sw,
                                        ln_scale + D, ln_bias + D,
                                        nullptr, nullptr, nullptr,
                                        nullptr, nullptr, nullptr, out);
}